// Round 9
// baseline (665.190 us; speedup 1.0000x reference)
//
#include <hip/hip_runtime.h>
#include <hip/hip_cooperative_groups.h>
#include <stdint.h>

namespace cg = cooperative_groups;

#define DIM 128

static constexpr long long NTOT = 299593LL;

using bf16x8 = __attribute__((ext_vector_type(8))) __bf16;
using f32x4  = __attribute__((ext_vector_type(4))) float;

__device__ __forceinline__ float relu(float x){ return x > 0.f ? x : 0.f; }
__device__ __forceinline__ __bf16 tobf(float x){ return (__bf16)x; }

__device__ __forceinline__ void mfma_acc(f32x4& acc, bf16x8 a, bf16x8 b){
    acc = __builtin_amdgcn_mfma_f32_16x16x32_bf16(a, b, acc, 0, 0, 0);
}

// XOR swizzle for a 16x128 bf16 LDS slice (16B-chunk granularity, bijective).
// Same function on write and read. (R3..R8-proven)
__device__ __forceinline__ int swz(int row, int col){
    return row*128 + (col ^ ((row & 7) << 3));
}

// ---- prep (R6/R7-proven): weights fp32->bf16 frag-major; root ctx = ones.
// Frag-major: element (r,c) -> ((nt*4+ks)*512 + lane*8 + j), nt=r>>4, l15=r&15,
// ks=c>>5, quad=(c>>3)&3, j=c&7, lane=quad*16+l15.
__global__ __launch_bounds__(256) void prep_kernel(
    const float* __restrict__ Ws, const float* __restrict__ Wc,
    const float* __restrict__ Wx, const float* __restrict__ Wf,
    __bf16* __restrict__ wfm, __bf16* __restrict__ ctx)
{
    int idx = blockIdx.x*256 + threadIdx.x;
    if (idx < 81920){
        int sel = idx >> 14;                // 0:Ws 1:Wc 2:Wx 3:Wf-h0 4:Wf-h1
        int d   = idx & 16383;
        int j = d & 7, ln = (d >> 3) & 63, f = d >> 9;
        int r = (f >> 2)*16 + (ln & 15);
        int c = (f & 3)*32 + (ln >> 4)*8 + j;
        float v;
        if      (sel == 0) v = Ws[r*128 + c];
        else if (sel == 1) v = Wc[r*128 + c];
        else if (sel == 2) v = Wx[r*128 + c];
        else if (sel == 3) v = Wf[r*256 + c];
        else               v = Wf[r*256 + 128 + c];
        wfm[idx] = tobf(v);
    } else if (idx < 82048){
        ctx[idx - 81920] = tobf(1.0f);      // root context row
    }
}

// ================== per-level wave-task bodies (R4/R6/R7-proven correct) ==============

// up task: 64 children -> GEMM1(Ws)+sib-mean -> 16 sib rows in wave's LDS slice ->
// GEMM2(Wc) -> 8 parents, guarded. lds_w holds Ws @0 AND Wc @16384.
__device__ __forceinline__ void up_level_task(
    const __bf16* __restrict__ lds_w,
    __bf16* __restrict__ sib,
    const float* __restrict__ init,
    const float* __restrict__ bsr, const float* __restrict__ bcr,
    __bf16* __restrict__ agg,
    long long task, long long cb, long long pb, long long n_par,
    int lane, int quad, int l15)
{
    const long long n_child = n_par*8;
    const long long c0 = task*64;
    bf16x8 af[4][4];
    #pragma unroll
    for (int tt = 0; tt < 4; ++tt){
        long long r = c0 + tt*16 + l15;
        if (r >= n_child) r = n_child - 1;
        const __bf16* p = agg + (cb + r)*DIM + quad*8;
        #pragma unroll
        for (int ks = 0; ks < 4; ++ks)
            af[tt][ks] = *(const bf16x8*)(p + ks*32);
    }
    #pragma unroll
    for (int h = 0; h < 2; ++h){
        f32x4 acc[2][8];
        #pragma unroll
        for (int u = 0; u < 2; ++u)
            #pragma unroll
            for (int i = 0; i < 8; ++i) acc[u][i] = f32x4{0.f,0.f,0.f,0.f};
        #pragma unroll
        for (int ks = 0; ks < 4; ++ks){
            #pragma unroll
            for (int nt = 0; nt < 8; ++nt){
                bf16x8 b = *(const bf16x8*)&lds_w[((nt*4+ks)<<9) + lane*8];
                mfma_acc(acc[0][nt], af[2*h+0][ks], b);
                mfma_acc(acc[1][nt], af[2*h+1][ks], b);
            }
        }
        #pragma unroll
        for (int u = 0; u < 2; ++u){
            const int row = (2*h+u)*4 + quad;   // local sib row 0..15
            #pragma unroll
            for (int nt = 0; nt < 8; ++nt){
                float b = bsr[nt];
                float s = relu(acc[u][nt][0]+b) + relu(acc[u][nt][1]+b)
                        + relu(acc[u][nt][2]+b) + relu(acc[u][nt][3]+b);
                sib[swz(row, nt*16 + l15)] = tobf(s*0.25f);
            }
        }
    }
    bf16x8 a2[4];
    #pragma unroll
    for (int ks = 0; ks < 4; ++ks)
        a2[ks] = *(const bf16x8*)&sib[swz(l15, ks*32 + quad*8)];
    f32x4 ac2[8];
    #pragma unroll
    for (int i = 0; i < 8; ++i) ac2[i] = f32x4{0.f,0.f,0.f,0.f};
    #pragma unroll
    for (int ks = 0; ks < 4; ++ks){
        #pragma unroll
        for (int nt = 0; nt < 8; ++nt){
            bf16x8 b = *(const bf16x8*)&lds_w[16384 + ((nt*4+ks)<<9) + lane*8];
            mfma_acc(ac2[nt], a2[ks], b);
        }
    }
    const long long p0l = task*8 + quad*2, p1l = p0l + 1;
    #pragma unroll
    for (int nt = 0; nt < 8; ++nt){
        int col = nt*16 + l15;
        float b = bcr[nt];
        float r0_ = relu(ac2[nt][0]+b), r1_ = relu(ac2[nt][1]+b);
        float r2_ = relu(ac2[nt][2]+b), r3_ = relu(ac2[nt][3]+b);
        if (p0l < n_par){
            long long gr = pb + p0l;
            agg[gr*DIM + col] = tobf(init[gr*DIM + col] + 0.5f*(r0_+r1_));
        }
        if (p1l < n_par){
            long long gr = pb + p1l;
            agg[gr*DIM + col] = tobf(init[gr*DIM + col] + 0.5f*(r2_+r3_));
        }
    }
}

// down task: 16 parents -> ctxh in wave's LDS slice -> 8 child tiles, guarded.
__device__ __forceinline__ void down_level_task(
    const __bf16* __restrict__ lds_w,   // Wx frag-major
    __bf16* __restrict__ ch,
    const float* __restrict__ bxr,
    const __bf16* __restrict__ agg, __bf16* __restrict__ ctx,
    long long task, long long pb, long long cb, long long n_par,
    int lane, int quad, int l15)
{
    const long long n_child = n_par*8;
    {
        long long p = task*16 + l15;
        if (p >= n_par) p = n_par - 1;
        bf16x8 ap[4];
        #pragma unroll
        for (int ks = 0; ks < 4; ++ks)
            ap[ks] = *(const bf16x8*)(ctx + (pb + p)*DIM + ks*32 + quad*8);
        f32x4 acp[8];
        #pragma unroll
        for (int i = 0; i < 8; ++i) acp[i] = f32x4{0.f,0.f,0.f,0.f};
        #pragma unroll
        for (int ks = 0; ks < 4; ++ks){
            #pragma unroll
            for (int nt = 0; nt < 8; ++nt){
                bf16x8 b = *(const bf16x8*)&lds_w[((nt*4+ks)<<9) + lane*8];
                mfma_acc(acp[nt], ap[ks], b);
            }
        }
        #pragma unroll
        for (int nt = 0; nt < 8; ++nt){
            float b = bxr[nt];
            #pragma unroll
            for (int rg = 0; rg < 4; ++rg)
                ch[swz(quad*4 + rg, nt*16 + l15)] = tobf(relu(acp[nt][rg] + b));
        }
    }
    #pragma unroll 1
    for (int ct = 0; ct < 8; ++ct){
        const long long ch0 = task*128 + ct*16;
        if (ch0 >= n_child) break;
        bf16x8 a[4];
        {
            long long r = ch0 + l15;
            if (r >= n_child) r = n_child - 1;
            const __bf16* p = agg + (cb + r)*DIM + quad*8;
            #pragma unroll
            for (int ks = 0; ks < 4; ++ks)
                a[ks] = *(const bf16x8*)(p + ks*32);
        }
        f32x4 acc[8];
        #pragma unroll
        for (int i = 0; i < 8; ++i) acc[i] = f32x4{0.f,0.f,0.f,0.f};
        #pragma unroll
        for (int ks = 0; ks < 4; ++ks){
            #pragma unroll
            for (int nt = 0; nt < 8; ++nt){
                bf16x8 b = *(const bf16x8*)&lds_w[((nt*4+ks)<<9) + lane*8];
                mfma_acc(acc[nt], a[ks], b);
            }
        }
        const long long rb = ch0 + quad*4;
        const int p_loc = ct*2 + (quad >> 1);
        #pragma unroll
        for (int nt = 0; nt < 8; ++nt){
            int col = nt*16 + l15;
            float b = bxr[nt];
            float h0 = relu(acc[nt][0]+b), h1 = relu(acc[nt][1]+b);
            float h2 = relu(acc[nt][2]+b), h3 = relu(acc[nt][3]+b);
            float s = h0 + h1 + h2 + h3;
            float chv = (float)ch[swz(p_loc, col)];
            if (rb   < n_child) ctx[(cb + rb  )*DIM + col] = tobf((chv + s - h0)*0.25f);
            if (rb+1 < n_child) ctx[(cb + rb+1)*DIM + col] = tobf((chv + s - h1)*0.25f);
            if (rb+2 < n_child) ctx[(cb + rb+2)*DIM + col] = tobf((chv + s - h2)*0.25f);
            if (rb+3 < n_child) ctx[(cb + rb+3)*DIM + col] = tobf((chv + s - h3)*0.25f);
        }
    }
}

// ================== upleaf v3 (R8-proven): barrier-free wave-fused, no leaf-agg store ==
__global__ __launch_bounds__(256, 2) void upleaf_kernel(
    const __bf16* __restrict__ wfm,     // Ws @0, Wc @16384 (frag-major)
    const float* __restrict__ init,
    const float* __restrict__ bs, const float* __restrict__ bc,
    __bf16* __restrict__ agg)
{
    __shared__ __attribute__((aligned(16))) __bf16 lds_w[32768];    // Ws | Wc
    __shared__ __attribute__((aligned(16))) __bf16 lds_sib[4*2048]; // per-wave 16x128
    {
        const int t = threadIdx.x;
        #pragma unroll
        for (int i = 0; i < 16; ++i){
            int c = i*256 + t;
            *((uint4*)lds_w + c) = *((const uint4*)wfm + c);
        }
    }
    __syncthreads();                        // the ONLY barrier

    const int t = threadIdx.x, w = t>>6, lane = t&63, quad = lane>>4, l15 = lane&15;
    const int sboff = w*2048;

    float bsr[8], bcr[8];
    #pragma unroll
    for (int nt = 0; nt < 8; ++nt){ bsr[nt] = bs[nt*16 + l15]; bcr[nt] = bc[nt*16 + l15]; }

    const long long gw = blockIdx.x*4 + w;  // 4096 waves, 64 rows each (exact)
    const long long r0 = gw*64;
    const long long cb = 37449LL;           // leaf base
    const long long pb = 4681LL + gw*8;     // this wave's 8 parents (global rows)

    const long long pr0 = pb + quad*2, pr1 = pr0 + 1;
    float pinit0[8], pinit1[8];
    #pragma unroll
    for (int nt = 0; nt < 8; ++nt){
        pinit0[nt] = init[pr0*DIM + nt*16 + l15];
        pinit1[nt] = init[pr1*DIM + nt*16 + l15];
    }

    bf16x8 af[4][4];
    #pragma unroll
    for (int tt = 0; tt < 4; ++tt){
        const long long base = (cb + r0 + tt*16 + l15)*DIM + quad*8;
        const float* p = init + base;
        #pragma unroll
        for (int ks = 0; ks < 4; ++ks){
            float4 v0 = *(const float4*)(p + ks*32);
            float4 v1 = *(const float4*)(p + ks*32 + 4);
            bf16x8 a;
            a[0]=tobf(v0.x); a[1]=tobf(v0.y); a[2]=tobf(v0.z); a[3]=tobf(v0.w);
            a[4]=tobf(v1.x); a[5]=tobf(v1.y); a[6]=tobf(v1.z); a[7]=tobf(v1.w);
            af[tt][ks] = a;                 // no leaf-agg store (R8 deletion)
        }
    }

    #pragma unroll
    for (int h = 0; h < 2; ++h){
        f32x4 acc[2][8];
        #pragma unroll
        for (int u = 0; u < 2; ++u)
            #pragma unroll
            for (int i = 0; i < 8; ++i) acc[u][i] = f32x4{0.f,0.f,0.f,0.f};
        #pragma unroll
        for (int ks = 0; ks < 4; ++ks){
            #pragma unroll
            for (int nt = 0; nt < 8; ++nt){
                bf16x8 b = *(const bf16x8*)&lds_w[((nt*4+ks)<<9) + lane*8];
                mfma_acc(acc[0][nt], af[2*h+0][ks], b);
                mfma_acc(acc[1][nt], af[2*h+1][ks], b);
            }
        }
        #pragma unroll
        for (int u = 0; u < 2; ++u){
            const int row = (2*h+u)*4 + quad;   // local sib row 0..15
            #pragma unroll
            for (int nt = 0; nt < 8; ++nt){
                float b = bsr[nt];
                float s = relu(acc[u][nt][0]+b) + relu(acc[u][nt][1]+b)
                        + relu(acc[u][nt][2]+b) + relu(acc[u][nt][3]+b);
                lds_sib[sboff + swz(row, nt*16 + l15)] = tobf(s*0.25f);
            }
        }
    }

    bf16x8 a2[4];
    #pragma unroll
    for (int ks = 0; ks < 4; ++ks)
        a2[ks] = *(const bf16x8*)&lds_sib[sboff + swz(l15, ks*32 + quad*8)];
    f32x4 ac2[8];
    #pragma unroll
    for (int i = 0; i < 8; ++i) ac2[i] = f32x4{0.f,0.f,0.f,0.f};
    #pragma unroll
    for (int ks = 0; ks < 4; ++ks){
        #pragma unroll
        for (int nt = 0; nt < 8; ++nt){
            bf16x8 b = *(const bf16x8*)&lds_w[16384 + ((nt*4+ks)<<9) + lane*8];
            mfma_acc(ac2[nt], a2[ks], b);
        }
    }
    #pragma unroll
    for (int nt = 0; nt < 8; ++nt){
        int col = nt*16 + l15;
        float b = bcr[nt];
        float r0_ = relu(ac2[nt][0]+b), r1_ = relu(ac2[nt][1]+b);
        float r2_ = relu(ac2[nt][2]+b), r3_ = relu(ac2[nt][3]+b);
        agg[pr0*DIM + col] = tobf(pinit0[nt] + 0.5f*(r0_+r1_));
        agg[pr1*DIM + col] = tobf(pinit1[nt] + 0.5f*(r2_+r3_));
    }
}

// ================== up_small: levels 4..0, COOPERATIVE grid.sync between levels =====
__global__ __launch_bounds__(256, 2) void up_small_kernel(
    const __bf16* __restrict__ wfm,     // Ws|Wc frag-major
    const float* __restrict__ init,
    const float* __restrict__ bs, const float* __restrict__ bc,
    __bf16* __restrict__ agg)
{
    cg::grid_group grid = cg::this_grid();
    __shared__ __attribute__((aligned(16))) __bf16 lds_w[32768];
    __shared__ __attribute__((aligned(16))) __bf16 lds_sib[4*2048];
    {
        const int t = threadIdx.x;
        #pragma unroll
        for (int i = 0; i < 16; ++i)
            ((uint4*)lds_w)[i*256 + t] = ((const uint4*)wfm)[i*256 + t];
    }
    __syncthreads();

    const int t = threadIdx.x, w = t>>6, lane = t&63, quad = lane>>4, l15 = lane&15;
    const int nblk = gridDim.x;                  // 256
    const long long gw = (long long)w*nblk + blockIdx.x;   // spread waves across CUs

    float bsr[8], bcr[8];
    #pragma unroll
    for (int nt = 0; nt < 8; ++nt){ bsr[nt] = bs[nt*16 + l15]; bcr[nt] = bc[nt*16 + l15]; }

    #pragma unroll 1
    for (int l = 4; l >= 0; --l){
        const long long n_par = 1LL << (3*l);
        const long long cb = ((1LL << (3*(l+1))) - 1)/7;
        const long long pb = ((1LL << (3*l)) - 1)/7;
        const long long ntask = (n_par + 7) >> 3;
        if (gw < ntask)
            up_level_task(lds_w, lds_sib + w*2048, init, bsr, bcr, agg,
                          gw, cb, pb, n_par, lane, quad, l15);
        if (l > 0) grid.sync();
    }
}

// ================== down_small: levels 0..4, COOPERATIVE grid.sync between levels ===
__global__ __launch_bounds__(256, 2) void down_small_kernel(
    const __bf16* __restrict__ wfm,     // Wx frag-major
    const float* __restrict__ bx,
    const __bf16* __restrict__ agg, __bf16* __restrict__ ctx)
{
    cg::grid_group grid = cg::this_grid();
    __shared__ __attribute__((aligned(16))) __bf16 lds_w[16384];
    __shared__ __attribute__((aligned(16))) __bf16 lds_ch[4*2048];
    {
        const int t = threadIdx.x;
        #pragma unroll
        for (int i = 0; i < 8; ++i)
            ((uint4*)lds_w)[i*256 + t] = ((const uint4*)wfm)[i*256 + t];
    }
    __syncthreads();

    const int t = threadIdx.x, w = t>>6, lane = t&63, quad = lane>>4, l15 = lane&15;
    const int nblk = gridDim.x;                  // 256
    const long long gw = (long long)w*nblk + blockIdx.x;

    float bxr[8];
    #pragma unroll
    for (int nt = 0; nt < 8; ++nt) bxr[nt] = bx[nt*16 + l15];

    #pragma unroll 1
    for (int l = 0; l < 5; ++l){
        const long long n_par = 1LL << (3*l);
        const long long pb = ((1LL << (3*l)) - 1)/7;
        const long long cb = ((1LL << (3*(l+1))) - 1)/7;
        const long long ntask = (n_par + 15) >> 4;
        if (gw < ntask)
            down_level_task(lds_w, lds_ch + w*2048, bxr, agg, ctx,
                            gw, pb, cb, n_par, lane, quad, l15);
        if (l < 4) grid.sync();
    }
}

// ================== downfinal v3 (R8-proven): leaf down+final head; A from init fp32 ==
__global__ __launch_bounds__(512, 2) void downfinal_kernel(
    const __bf16* __restrict__ wx,      // Wx frag-major
    const __bf16* __restrict__ wf,      // Wf frag-major [h0|h1]
    const float* __restrict__ bx, const float* __restrict__ bf_,
    const float* __restrict__ Wh, const float* __restrict__ bh,
    const float* __restrict__ init, const __bf16* __restrict__ ctx,
    float* __restrict__ out)
{
    __shared__ __attribute__((aligned(16))) __bf16 lds_wx[16384];
    __shared__ __attribute__((aligned(16))) __bf16 lds_wf[32768];
    __shared__ __attribute__((aligned(16))) __bf16 lds_st[8*2048];  // per-wave 16x128
    {
        const int t = threadIdx.x;
        #pragma unroll
        for (int i = 0; i < 4; ++i)
            ((uint4*)lds_wx)[i*512+t] = ((const uint4*)wx)[i*512+t];
        #pragma unroll
        for (int i = 0; i < 8; ++i)
            ((uint4*)lds_wf)[i*512+t] = ((const uint4*)wf)[i*512+t];
    }
    __syncthreads();                        // the ONLY barrier

    const int t = threadIdx.x, w = t>>6, lane = t&63, quad = lane>>4, l15 = lane&15;
    const int stoff = w*2048;
    const long long task = (long long)blockIdx.x*8 + w;     // 0..2047
    const long long cb = 37449LL;
    const long long pg = 4681LL + task*16;

    float bxr[8], bfr[8], whr[8];
    #pragma unroll
    for (int nt = 0; nt < 8; ++nt){
        bxr[nt] = bx[nt*16 + l15];
        bfr[nt] = bf_[nt*16 + l15];
        whr[nt] = Wh[nt*16 + l15];
    }
    const float bb = bh[0];

    // ctxh for this wave's 16 parents -> registers (chv[nt][rg], rows quad*4+rg)
    float chv[8][4];
    {
        bf16x8 ap[4];
        #pragma unroll
        for (int ks = 0; ks < 4; ++ks)
            ap[ks] = *(const bf16x8*)(ctx + (pg + l15)*DIM + ks*32 + quad*8);
        f32x4 acp[8];
        #pragma unroll
        for (int i = 0; i < 8; ++i) acp[i] = f32x4{0.f,0.f,0.f,0.f};
        #pragma unroll
        for (int ks = 0; ks < 4; ++ks){
            #pragma unroll
            for (int nt = 0; nt < 8; ++nt){
                bf16x8 b = *(const bf16x8*)&lds_wx[((nt*4+ks)<<9) + lane*8];
                mfma_acc(acp[nt], ap[ks], b);
            }
        }
        #pragma unroll
        for (int nt = 0; nt < 8; ++nt){
            #pragma unroll
            for (int rg = 0; rg < 4; ++rg)
                chv[nt][rg] = relu(acp[nt][rg] + bxr[nt]);
        }
    }

    // tile body: P = ct&1 (static chv reg indices); src lane = (ct>>1)*16 + l15
#define DF_TILE(CT, P, AF)                                                      \
    {                                                                           \
        f32x4 acch[8];                                                          \
        _Pragma("unroll") for (int i = 0; i < 8; ++i) acch[i] = f32x4{0.f,0.f,0.f,0.f}; \
        _Pragma("unroll") for (int ks = 0; ks < 4; ++ks){                       \
            _Pragma("unroll") for (int nt = 0; nt < 8; ++nt){                   \
                bf16x8 b = *(const bf16x8*)&lds_wx[((nt*4+ks)<<9) + lane*8];    \
                mfma_acc(acch[nt], AF[ks], b);                                  \
            }                                                                   \
        }                                                                       \
        const int srcl = ((CT)>>1)*16 + l15;                                    \
        _Pragma("unroll") for (int nt = 0; nt < 8; ++nt){                       \
            float vA = __shfl(chv[nt][2*(P)],   srcl);                          \
            float vB = __shfl(chv[nt][2*(P)+1], srcl);                          \
            float ch = (quad >= 2) ? vB : vA;                                   \
            float b = bxr[nt];                                                  \
            float h0 = relu(acch[nt][0]+b), h1 = relu(acch[nt][1]+b);           \
            float h2 = relu(acch[nt][2]+b), h3 = relu(acch[nt][3]+b);           \
            float s = h0+h1+h2+h3;                                              \
            int col = nt*16 + l15;                                              \
            lds_st[stoff + swz(quad*4+0, col)] = tobf((ch+s-h0)*0.25f);         \
            lds_st[stoff + swz(quad*4+1, col)] = tobf((ch+s-h1)*0.25f);         \
            lds_st[stoff + swz(quad*4+2, col)] = tobf((ch+s-h2)*0.25f);         \
            lds_st[stoff + swz(quad*4+3, col)] = tobf((ch+s-h3)*0.25f);         \
        }                                                                       \
        bf16x8 cf[4];                                                           \
        _Pragma("unroll") for (int ks = 0; ks < 4; ++ks)                        \
            cf[ks] = *(const bf16x8*)&lds_st[stoff + swz(l15, ks*32 + quad*8)]; \
        f32x4 accf[8];                                                          \
        _Pragma("unroll") for (int i = 0; i < 8; ++i) accf[i] = f32x4{0.f,0.f,0.f,0.f}; \
        _Pragma("unroll") for (int ks = 0; ks < 4; ++ks){                       \
            _Pragma("unroll") for (int nt = 0; nt < 8; ++nt){                   \
                bf16x8 b0 = *(const bf16x8*)&lds_wf[((nt*4+ks)<<9) + lane*8];           \
                bf16x8 b1 = *(const bf16x8*)&lds_wf[16384 + ((nt*4+ks)<<9) + lane*8];   \
                mfma_acc(accf[nt], cf[ks], b0);                                 \
                mfma_acc(accf[nt], AF[ks], b1);                                 \
            }                                                                   \
        }                                                                       \
        float p0=0.f,p1=0.f,p2=0.f,p3=0.f;                                      \
        _Pragma("unroll") for (int nt = 0; nt < 8; ++nt){                       \
            float b = bfr[nt], wh = whr[nt];                                    \
            p0 += relu(accf[nt][0]+b)*wh; p1 += relu(accf[nt][1]+b)*wh;         \
            p2 += relu(accf[nt][2]+b)*wh; p3 += relu(accf[nt][3]+b)*wh;         \
        }                                                                       \
        _Pragma("unroll") for (int m = 1; m < 16; m <<= 1){                     \
            p0 += __shfl_xor(p0, m); p1 += __shfl_xor(p1, m);                   \
            p2 += __shfl_xor(p2, m); p3 += __shfl_xor(p3, m);                   \
        }                                                                       \
        if (l15 == 0){                                                          \
            long long r = cb + task*128 + (long long)(CT)*16 + quad*4;          \
            out[r] = p0 + bb; out[r+1] = p1 + bb;                               \
            out[r+2] = p2 + bb; out[r+3] = p3 + bb;                             \
        }                                                                       \
    }

    auto LOADA = [&](bf16x8* d, int ct){
        const float* p = init + (cb + task*128 + ct*16 + l15)*DIM + quad*8;
        #pragma unroll
        for (int ks = 0; ks < 4; ++ks){
            float4 v0 = *(const float4*)(p + ks*32);
            float4 v1 = *(const float4*)(p + ks*32 + 4);
            bf16x8 a;
            a[0]=tobf(v0.x); a[1]=tobf(v0.y); a[2]=tobf(v0.z); a[3]=tobf(v0.w);
            a[4]=tobf(v1.x); a[5]=tobf(v1.y); a[6]=tobf(v1.z); a[7]=tobf(v1.w);
            d[ks] = a;
        }
    };

    bf16x8 aA[4], aB[4];
    LOADA(aA, 0);
    #pragma unroll 1
    for (int cp = 0; cp < 4; ++cp){
        const int ct0 = cp*2, ct1 = ct0 + 1;
        LOADA(aB, ct1);
        DF_TILE(ct0, 0, aA);
        if (cp < 3) LOADA(aA, ct0 + 2);
        DF_TILE(ct1, 1, aB);
    }
#undef DF_TILE
}

// ================== final for NON-LEAF rows only (R4..R8-proven, streaming) ==========
__global__ __launch_bounds__(512, 2) void final_nl_kernel(
    const __bf16* __restrict__ wfm,     // Wf frag-major, 2 halves x 16384
    const __bf16* __restrict__ ctx, const __bf16* __restrict__ agg,
    const float* __restrict__ bf_,
    const float* __restrict__ Wh, const float* __restrict__ bh,
    float* __restrict__ out, long long nrows)
{
    __shared__ __attribute__((aligned(16))) __bf16 lds_w[32768];
    {
        const int t = threadIdx.x;
        #pragma unroll
        for (int i = 0; i < 8; ++i){
            int c = i*512 + t;
            *((uint4*)lds_w + c) = *((const uint4*)wfm + c);
        }
    }
    __syncthreads();
    const int t = threadIdx.x, w = t>>6, lane = t&63, quad = lane>>4, l15 = lane&15;
    float bfr[8], whr[8];
    #pragma unroll
    for (int nt = 0; nt < 8; ++nt){
        bfr[nt] = bf_[nt*16 + l15];
        whr[nt] = Wh[nt*16 + l15];
    }
    const float bb = bh[0];
    const long long stride = (long long)gridDim.x*8;
    #pragma unroll 1
    for (long long tile = blockIdx.x*8 + w; ; tile += stride){
        const long long r0 = tile*32;
        if (r0 >= nrows) break;
        f32x4 acc[2][8];
        #pragma unroll
        for (int tt = 0; tt < 2; ++tt)
            #pragma unroll
            for (int i = 0; i < 8; ++i) acc[tt][i] = f32x4{0.f,0.f,0.f,0.f};
        #pragma unroll
        for (int half = 0; half < 2; ++half){
            const __bf16* src = half ? agg : ctx;
            bf16x8 a[2][4];
            #pragma unroll
            for (int tt = 0; tt < 2; ++tt){
                long long r = r0 + tt*16 + l15;
                if (r >= nrows) r = nrows - 1;
                #pragma unroll
                for (int ks = 0; ks < 4; ++ks)
                    a[tt][ks] = *(const bf16x8*)(src + r*DIM + ks*32 + quad*8);
            }
            #pragma unroll
            for (int ks = 0; ks < 4; ++ks){
                #pragma unroll
                for (int nt = 0; nt < 8; ++nt){
                    bf16x8 b = *(const bf16x8*)&lds_w[half*16384 + ((nt*4+ks)<<9) + lane*8];
                    mfma_acc(acc[0][nt], a[0][ks], b);
                    mfma_acc(acc[1][nt], a[1][ks], b);
                }
            }
        }
        #pragma unroll
        for (int tt = 0; tt < 2; ++tt){
            float p0 = 0.f, p1 = 0.f, p2 = 0.f, p3 = 0.f;
            #pragma unroll
            for (int nt = 0; nt < 8; ++nt){
                float b = bfr[nt], wh = whr[nt];
                p0 += relu(acc[tt][nt][0]+b)*wh;
                p1 += relu(acc[tt][nt][1]+b)*wh;
                p2 += relu(acc[tt][nt][2]+b)*wh;
                p3 += relu(acc[tt][nt][3]+b)*wh;
            }
            #pragma unroll
            for (int m = 1; m < 16; m <<= 1){
                p0 += __shfl_xor(p0, m);
                p1 += __shfl_xor(p1, m);
                p2 += __shfl_xor(p2, m);
                p3 += __shfl_xor(p3, m);
            }
            if (l15 == 0){
                long long r = r0 + tt*16 + quad*4;
                if (r   < nrows) out[r  ] = p0 + bb;
                if (r+1 < nrows) out[r+1] = p1 + bb;
                if (r+2 < nrows) out[r+2] = p2 + bb;
                if (r+3 < nrows) out[r+3] = p3 + bb;
            }
        }
    }
}

extern "C" void kernel_launch(void* const* d_in, const int* in_sizes, int n_in,
                              void* d_out, int out_size, void* d_ws, size_t ws_size,
                              hipStream_t stream)
{
    const float* init = (const float*)d_in[0];
    const float* Ws  = (const float*)d_in[1];
    const float* bs  = (const float*)d_in[2];
    const float* Wc  = (const float*)d_in[3];
    const float* bc  = (const float*)d_in[4];
    const float* Wx  = (const float*)d_in[5];
    const float* bx  = (const float*)d_in[6];
    const float* Wf  = (const float*)d_in[7];
    const float* bff = (const float*)d_in[8];
    const float* Wh  = (const float*)d_in[9];
    const float* bh  = (const float*)d_in[10];
    float* out = (float*)d_out;

    // ws layout: agg bf16 [N,128] | ctx bf16 [N,128] | wfm frag-major (81920)
    __bf16* agg = (__bf16*)d_ws;
    __bf16* ctx = agg + NTOT*DIM;
    __bf16* wfm = ctx + NTOT*DIM;
    __bf16* wfm_dn = wfm + 32768;           // Wx
    __bf16* wfm_wf = wfm + 49152;           // Wf halves

    prep_kernel<<<dim3(321), dim3(256), 0, stream>>>(Ws, Wc, Wx, Wf, wfm, ctx);

    // ---- up: leaf level barrier-free wave-fused; levels 4..0 in ONE cooperative kernel
    upleaf_kernel<<<dim3(1024), dim3(256), 0, stream>>>(wfm, init, bs, bc, agg);
    {
        void* args[] = {(void*)&wfm, (void*)&init, (void*)&bs, (void*)&bc, (void*)&agg};
        hipLaunchCooperativeKernel((void*)up_small_kernel, dim3(256), dim3(256),
                                   args, 0, stream);
    }
    // ---- down: levels 0..4 in ONE cooperative kernel; leaf fused with final head ----
    {
        void* args[] = {(void*)&wfm_dn, (void*)&bx, (void*)&agg, (void*)&ctx};
        hipLaunchCooperativeKernel((void*)down_small_kernel, dim3(256), dim3(256),
                                   args, 0, stream);
    }
    downfinal_kernel<<<dim3(256), dim3(512), 0, stream>>>(
        wfm_dn, wfm_wf, bx, bff, Wh, bh, init, ctx, out);
    final_nl_kernel<<<dim3(147), dim3(512), 0, stream>>>(
        wfm_wf, ctx, agg, bff, Wh, bh, out, 37449LL);
}

// Round 10
// 409.018 us; speedup vs baseline: 1.6263x; 1.6263x over previous
//
#include <hip/hip_runtime.h>
#include <stdint.h>

#define DIM 128
#define LPAD 136   // padded LDS row stride for the fused small-level kernels (round-0 proven)

static constexpr long long NTOT = 299593LL;

using bf16x8 = __attribute__((ext_vector_type(8))) __bf16;
using f32x4  = __attribute__((ext_vector_type(4))) float;

__device__ __forceinline__ float relu(float x){ return x > 0.f ? x : 0.f; }
__device__ __forceinline__ __bf16 tobf(float x){ return (__bf16)x; }

__device__ __forceinline__ void mfma_acc(f32x4& acc, bf16x8 a, bf16x8 b){
    acc = __builtin_amdgcn_mfma_f32_16x16x32_bf16(a, b, acc, 0, 0, 0);
}

// XOR swizzle for a 16x128 bf16 LDS slice (16B-chunk granularity, bijective).
// Same function on write and read. (R3..R8-proven)
__device__ __forceinline__ int swz(int row, int col){
    return row*128 + (col ^ ((row & 7) << 3));
}

// copy 128x128 bf16 weight (row stride src_stride) into padded LDS (stride LPAD)
// -- used by the fused small-level kernels (round-0 proven)
__device__ __forceinline__ void load_w_lds(const __bf16* __restrict__ wsrc,
                                           __bf16* lds, int src_stride){
    int t = threadIdx.x;
    #pragma unroll
    for (int i = 0; i < 8; ++i){
        int idx = t + i*256;                 // 2048 chunks of 8 bf16
        int row = idx >> 4, col8 = (idx & 15) << 3;
        *(uint4*)(&lds[row*LPAD + col8]) = *(const uint4*)(wsrc + row*src_stride + col8);
    }
}

// ---- prep (R3/R5/R8-proven): weights fp32->bf16 in BOTH row-major (fused small
// kernels) and frag-major (leaf/final kernels) layouts; root ctx = ones.
// Frag-major: element (r,c) -> ((nt*4+ks)*512 + lane*8 + j), nt=r>>4, l15=r&15,
// ks=c>>5, quad=(c>>3)&3, j=c&7, lane=quad*16+l15.
__global__ __launch_bounds__(256) void prep_kernel(
    const float* __restrict__ Ws, const float* __restrict__ Wc,
    const float* __restrict__ Wx, const float* __restrict__ Wf,
    __bf16* __restrict__ wts, __bf16* __restrict__ ctx)
{
    int idx = blockIdx.x*256 + threadIdx.x;
    if (idx < 81920){
        float v;
        if      (idx < 16384) v = Ws[idx];
        else if (idx < 32768) v = Wc[idx - 16384];
        else if (idx < 49152) v = Wx[idx - 32768];
        else                  v = Wf[idx - 49152];
        wts[idx] = tobf(v);
    } else if (idx < 163840){
        int d2 = idx - 81920;
        int sel = d2 >> 14;                 // 0:Ws 1:Wc 2:Wx 3:Wf-h0 4:Wf-h1
        int d   = d2 & 16383;
        int j = d & 7, ln = (d >> 3) & 63, f = d >> 9;
        int r = (f >> 2)*16 + (ln & 15);
        int c = (f & 3)*32 + (ln >> 4)*8 + j;
        float v;
        if      (sel == 0) v = Ws[r*128 + c];
        else if (sel == 1) v = Wc[r*128 + c];
        else if (sel == 2) v = Wx[r*128 + c];
        else if (sel == 3) v = Wf[r*256 + c];
        else               v = Wf[r*256 + 128 + c];
        wts[idx] = tobf(v);
    } else if (idx < 163968){
        ctx[idx - 163840] = tobf(1.0f);     // root context row
    }
}

// ================== upleaf v4: Ws-only in LDS (48KB -> 3 blocks/CU); GEMM2's Wc
// B-frags read from global (32KB, L2-hot across all blocks); no extra barriers.
// Leaf-agg store deleted (R8). setprio around MFMA clusters (T5: independent waves).
__global__ __launch_bounds__(256, 3) void upleaf_kernel(
    const __bf16* __restrict__ wfm,     // Ws @0, Wc @16384 (frag-major)
    const float* __restrict__ init,
    const float* __restrict__ bs, const float* __restrict__ bc,
    __bf16* __restrict__ agg)
{
    __shared__ __attribute__((aligned(16))) __bf16 lds_w[16384];    // Ws only (32KB)
    __shared__ __attribute__((aligned(16))) __bf16 lds_sib[4*2048]; // per-wave 16x128
    {
        const int t = threadIdx.x;
        #pragma unroll
        for (int i = 0; i < 8; ++i){
            int c = i*256 + t;
            *((uint4*)lds_w + c) = *((const uint4*)wfm + c);
        }
    }
    __syncthreads();                        // the ONLY barrier

    const int t = threadIdx.x, w = t>>6, lane = t&63, quad = lane>>4, l15 = lane&15;
    const int sboff = w*2048;
    const __bf16* __restrict__ wcg = wfm + 16384;   // Wc frag-major, global (L2)

    float bsr[8], bcr[8];
    #pragma unroll
    for (int nt = 0; nt < 8; ++nt){ bsr[nt] = bs[nt*16 + l15]; bcr[nt] = bc[nt*16 + l15]; }

    const long long gw = blockIdx.x*4 + w;  // 4096 waves, 64 rows each (exact)
    const long long r0 = gw*64;
    const long long cb = 37449LL;           // leaf base
    const long long pb = 4681LL + gw*8;     // this wave's 8 parents (global rows)

    const long long pr0 = pb + quad*2, pr1 = pr0 + 1;
    float pinit0[8], pinit1[8];
    #pragma unroll
    for (int nt = 0; nt < 8; ++nt){
        pinit0[nt] = init[pr0*DIM + nt*16 + l15];
        pinit1[nt] = init[pr1*DIM + nt*16 + l15];
    }

    bf16x8 af[4][4];
    #pragma unroll
    for (int tt = 0; tt < 4; ++tt){
        const long long base = (cb + r0 + tt*16 + l15)*DIM + quad*8;
        const float* p = init + base;
        #pragma unroll
        for (int ks = 0; ks < 4; ++ks){
            float4 v0 = *(const float4*)(p + ks*32);
            float4 v1 = *(const float4*)(p + ks*32 + 4);
            bf16x8 a;
            a[0]=tobf(v0.x); a[1]=tobf(v0.y); a[2]=tobf(v0.z); a[3]=tobf(v0.w);
            a[4]=tobf(v1.x); a[5]=tobf(v1.y); a[6]=tobf(v1.z); a[7]=tobf(v1.w);
            af[tt][ks] = a;                 // no leaf-agg store (R8 deletion)
        }
    }

    #pragma unroll
    for (int h = 0; h < 2; ++h){
        f32x4 acc[2][8];
        #pragma unroll
        for (int u = 0; u < 2; ++u)
            #pragma unroll
            for (int i = 0; i < 8; ++i) acc[u][i] = f32x4{0.f,0.f,0.f,0.f};
        __builtin_amdgcn_s_setprio(1);
        #pragma unroll
        for (int ks = 0; ks < 4; ++ks){
            #pragma unroll
            for (int nt = 0; nt < 8; ++nt){
                bf16x8 b = *(const bf16x8*)&lds_w[((nt*4+ks)<<9) + lane*8];
                mfma_acc(acc[0][nt], af[2*h+0][ks], b);
                mfma_acc(acc[1][nt], af[2*h+1][ks], b);
            }
        }
        __builtin_amdgcn_s_setprio(0);
        #pragma unroll
        for (int u = 0; u < 2; ++u){
            const int row = (2*h+u)*4 + quad;   // local sib row 0..15
            #pragma unroll
            for (int nt = 0; nt < 8; ++nt){
                float b = bsr[nt];
                float s = relu(acc[u][nt][0]+b) + relu(acc[u][nt][1]+b)
                        + relu(acc[u][nt][2]+b) + relu(acc[u][nt][3]+b);
                lds_sib[sboff + swz(row, nt*16 + l15)] = tobf(s*0.25f);
            }
        }
    }

    bf16x8 a2[4];
    #pragma unroll
    for (int ks = 0; ks < 4; ++ks)
        a2[ks] = *(const bf16x8*)&lds_sib[sboff + swz(l15, ks*32 + quad*8)];
    f32x4 ac2[8];
    #pragma unroll
    for (int i = 0; i < 8; ++i) ac2[i] = f32x4{0.f,0.f,0.f,0.f};
    __builtin_amdgcn_s_setprio(1);
    #pragma unroll
    for (int ks = 0; ks < 4; ++ks){
        #pragma unroll
        for (int nt = 0; nt < 8; ++nt){
            bf16x8 b = *(const bf16x8*)(wcg + ((nt*4+ks)<<9) + lane*8);  // Wc from L2
            mfma_acc(ac2[nt], a2[ks], b);
        }
    }
    __builtin_amdgcn_s_setprio(0);
    #pragma unroll
    for (int nt = 0; nt < 8; ++nt){
        int col = nt*16 + l15;
        float b = bcr[nt];
        float r0_ = relu(ac2[nt][0]+b), r1_ = relu(ac2[nt][1]+b);
        float r2_ = relu(ac2[nt][2]+b), r3_ = relu(ac2[nt][3]+b);
        agg[pr0*DIM + col] = tobf(pinit0[nt] + 0.5f*(r0_+r1_));
        agg[pr1*DIM + col] = tobf(pinit1[nt] + 0.5f*(r2_+r3_));
    }
}

// ================== downfinal v4 (R8 body + setprio around MFMA clusters) ==========
// Per wave: 16 parents (ctxh -> regs) then 8 child tiles: h=relu(Wx.A+bx);
// ctx=(ctxh+sum_sibs-h)/4 -> bf16 -> per-wave LDS transpose -> Wf GEMM (ctx half)
// + Wf GEMM (A half) -> out. A = bf16(init-leaf) converted in-register.
__global__ __launch_bounds__(512, 2) void downfinal_kernel(
    const __bf16* __restrict__ wx,      // Wx frag-major
    const __bf16* __restrict__ wf,      // Wf frag-major [h0|h1]
    const float* __restrict__ bx, const float* __restrict__ bf_,
    const float* __restrict__ Wh, const float* __restrict__ bh,
    const float* __restrict__ init, const __bf16* __restrict__ ctx,
    float* __restrict__ out)
{
    __shared__ __attribute__((aligned(16))) __bf16 lds_wx[16384];
    __shared__ __attribute__((aligned(16))) __bf16 lds_wf[32768];
    __shared__ __attribute__((aligned(16))) __bf16 lds_st[8*2048];  // per-wave 16x128
    {
        const int t = threadIdx.x;
        #pragma unroll
        for (int i = 0; i < 4; ++i)
            ((uint4*)lds_wx)[i*512+t] = ((const uint4*)wx)[i*512+t];
        #pragma unroll
        for (int i = 0; i < 8; ++i)
            ((uint4*)lds_wf)[i*512+t] = ((const uint4*)wf)[i*512+t];
    }
    __syncthreads();                        // the ONLY barrier

    const int t = threadIdx.x, w = t>>6, lane = t&63, quad = lane>>4, l15 = lane&15;
    const int stoff = w*2048;
    const long long task = (long long)blockIdx.x*8 + w;     // 0..2047
    const long long cb = 37449LL;
    const long long pg = 4681LL + task*16;

    float bxr[8], bfr[8], whr[8];
    #pragma unroll
    for (int nt = 0; nt < 8; ++nt){
        bxr[nt] = bx[nt*16 + l15];
        bfr[nt] = bf_[nt*16 + l15];
        whr[nt] = Wh[nt*16 + l15];
    }
    const float bb = bh[0];

    // ctxh for this wave's 16 parents -> registers (chv[nt][rg], rows quad*4+rg)
    float chv[8][4];
    {
        bf16x8 ap[4];
        #pragma unroll
        for (int ks = 0; ks < 4; ++ks)
            ap[ks] = *(const bf16x8*)(ctx + (pg + l15)*DIM + ks*32 + quad*8);
        f32x4 acp[8];
        #pragma unroll
        for (int i = 0; i < 8; ++i) acp[i] = f32x4{0.f,0.f,0.f,0.f};
        __builtin_amdgcn_s_setprio(1);
        #pragma unroll
        for (int ks = 0; ks < 4; ++ks){
            #pragma unroll
            for (int nt = 0; nt < 8; ++nt){
                bf16x8 b = *(const bf16x8*)&lds_wx[((nt*4+ks)<<9) + lane*8];
                mfma_acc(acp[nt], ap[ks], b);
            }
        }
        __builtin_amdgcn_s_setprio(0);
        #pragma unroll
        for (int nt = 0; nt < 8; ++nt){
            #pragma unroll
            for (int rg = 0; rg < 4; ++rg)
                chv[nt][rg] = relu(acp[nt][rg] + bxr[nt]);
        }
    }

    // tile body: P = ct&1 (static chv reg indices); src lane = (ct>>1)*16 + l15
#define DF_TILE(CT, P, AF)                                                      \
    {                                                                           \
        f32x4 acch[8];                                                          \
        _Pragma("unroll") for (int i = 0; i < 8; ++i) acch[i] = f32x4{0.f,0.f,0.f,0.f}; \
        __builtin_amdgcn_s_setprio(1);                                          \
        _Pragma("unroll") for (int ks = 0; ks < 4; ++ks){                       \
            _Pragma("unroll") for (int nt = 0; nt < 8; ++nt){                   \
                bf16x8 b = *(const bf16x8*)&lds_wx[((nt*4+ks)<<9) + lane*8];    \
                mfma_acc(acch[nt], AF[ks], b);                                  \
            }                                                                   \
        }                                                                       \
        __builtin_amdgcn_s_setprio(0);                                          \
        const int srcl = ((CT)>>1)*16 + l15;                                    \
        _Pragma("unroll") for (int nt = 0; nt < 8; ++nt){                       \
            float vA = __shfl(chv[nt][2*(P)],   srcl);                          \
            float vB = __shfl(chv[nt][2*(P)+1], srcl);                          \
            float ch = (quad >= 2) ? vB : vA;                                   \
            float b = bxr[nt];                                                  \
            float h0 = relu(acch[nt][0]+b), h1 = relu(acch[nt][1]+b);           \
            float h2 = relu(acch[nt][2]+b), h3 = relu(acch[nt][3]+b);           \
            float s = h0+h1+h2+h3;                                              \
            int col = nt*16 + l15;                                              \
            lds_st[stoff + swz(quad*4+0, col)] = tobf((ch+s-h0)*0.25f);         \
            lds_st[stoff + swz(quad*4+1, col)] = tobf((ch+s-h1)*0.25f);         \
            lds_st[stoff + swz(quad*4+2, col)] = tobf((ch+s-h2)*0.25f);         \
            lds_st[stoff + swz(quad*4+3, col)] = tobf((ch+s-h3)*0.25f);         \
        }                                                                       \
        bf16x8 cf[4];                                                           \
        _Pragma("unroll") for (int ks = 0; ks < 4; ++ks)                        \
            cf[ks] = *(const bf16x8*)&lds_st[stoff + swz(l15, ks*32 + quad*8)]; \
        f32x4 accf[8];                                                          \
        _Pragma("unroll") for (int i = 0; i < 8; ++i) accf[i] = f32x4{0.f,0.f,0.f,0.f}; \
        __builtin_amdgcn_s_setprio(1);                                          \
        _Pragma("unroll") for (int ks = 0; ks < 4; ++ks){                       \
            _Pragma("unroll") for (int nt = 0; nt < 8; ++nt){                   \
                bf16x8 b0 = *(const bf16x8*)&lds_wf[((nt*4+ks)<<9) + lane*8];           \
                bf16x8 b1 = *(const bf16x8*)&lds_wf[16384 + ((nt*4+ks)<<9) + lane*8];   \
                mfma_acc(accf[nt], cf[ks], b0);                                 \
                mfma_acc(accf[nt], AF[ks], b1);                                 \
            }                                                                   \
        }                                                                       \
        __builtin_amdgcn_s_setprio(0);                                          \
        float p0=0.f,p1=0.f,p2=0.f,p3=0.f;                                      \
        _Pragma("unroll") for (int nt = 0; nt < 8; ++nt){                       \
            float b = bfr[nt], wh = whr[nt];                                    \
            p0 += relu(accf[nt][0]+b)*wh; p1 += relu(accf[nt][1]+b)*wh;         \
            p2 += relu(accf[nt][2]+b)*wh; p3 += relu(accf[nt][3]+b)*wh;         \
        }                                                                       \
        _Pragma("unroll") for (int m = 1; m < 16; m <<= 1){                     \
            p0 += __shfl_xor(p0, m); p1 += __shfl_xor(p1, m);                   \
            p2 += __shfl_xor(p2, m); p3 += __shfl_xor(p3, m);                   \
        }                                                                       \
        if (l15 == 0){                                                          \
            long long r = cb + task*128 + (long long)(CT)*16 + quad*4;          \
            out[r] = p0 + bb; out[r+1] = p1 + bb;                               \
            out[r+2] = p2 + bb; out[r+3] = p3 + bb;                             \
        }                                                                       \
    }

    auto LOADA = [&](bf16x8* d, int ct){
        const float* p = init + (cb + task*128 + ct*16 + l15)*DIM + quad*8;
        #pragma unroll
        for (int ks = 0; ks < 4; ++ks){
            float4 v0 = *(const float4*)(p + ks*32);
            float4 v1 = *(const float4*)(p + ks*32 + 4);
            bf16x8 a;
            a[0]=tobf(v0.x); a[1]=tobf(v0.y); a[2]=tobf(v0.z); a[3]=tobf(v0.w);
            a[4]=tobf(v1.x); a[5]=tobf(v1.y); a[6]=tobf(v1.z); a[7]=tobf(v1.w);
            d[ks] = a;
        }
    };

    bf16x8 aA[4], aB[4];
    LOADA(aA, 0);
    #pragma unroll 1
    for (int cp = 0; cp < 4; ++cp){
        const int ct0 = cp*2, ct1 = ct0 + 1;
        LOADA(aB, ct1);
        DF_TILE(ct0, 0, aA);
        if (cp < 3) LOADA(aA, ct0 + 2);
        DF_TILE(ct1, 1, aB);
    }
#undef DF_TILE
}

// ================== final for NON-LEAF rows only (R4..R8-proven, streaming) ==========
__global__ __launch_bounds__(512, 2) void final_nl_kernel(
    const __bf16* __restrict__ wfm,     // Wf frag-major, 2 halves x 16384
    const __bf16* __restrict__ ctx, const __bf16* __restrict__ agg,
    const float* __restrict__ bf_,
    const float* __restrict__ Wh, const float* __restrict__ bh,
    float* __restrict__ out, long long nrows)
{
    __shared__ __attribute__((aligned(16))) __bf16 lds_w[32768];
    {
        const int t = threadIdx.x;
        #pragma unroll
        for (int i = 0; i < 8; ++i){
            int c = i*512 + t;
            *((uint4*)lds_w + c) = *((const uint4*)wfm + c);
        }
    }
    __syncthreads();
    const int t = threadIdx.x, w = t>>6, lane = t&63, quad = lane>>4, l15 = lane&15;
    float bfr[8], whr[8];
    #pragma unroll
    for (int nt = 0; nt < 8; ++nt){
        bfr[nt] = bf_[nt*16 + l15];
        whr[nt] = Wh[nt*16 + l15];
    }
    const float bb = bh[0];
    const long long stride = (long long)gridDim.x*8;
    #pragma unroll 1
    for (long long tile = blockIdx.x*8 + w; ; tile += stride){
        const long long r0 = tile*32;
        if (r0 >= nrows) break;
        f32x4 acc[2][8];
        #pragma unroll
        for (int tt = 0; tt < 2; ++tt)
            #pragma unroll
            for (int i = 0; i < 8; ++i) acc[tt][i] = f32x4{0.f,0.f,0.f,0.f};
        #pragma unroll
        for (int half = 0; half < 2; ++half){
            const __bf16* src = half ? agg : ctx;
            bf16x8 a[2][4];
            #pragma unroll
            for (int tt = 0; tt < 2; ++tt){
                long long r = r0 + tt*16 + l15;
                if (r >= nrows) r = nrows - 1;
                #pragma unroll
                for (int ks = 0; ks < 4; ++ks)
                    a[tt][ks] = *(const bf16x8*)(src + r*DIM + ks*32 + quad*8);
            }
            #pragma unroll
            for (int ks = 0; ks < 4; ++ks){
                #pragma unroll
                for (int nt = 0; nt < 8; ++nt){
                    bf16x8 b = *(const bf16x8*)&lds_w[half*16384 + ((nt*4+ks)<<9) + lane*8];
                    mfma_acc(acc[0][nt], a[0][ks], b);
                    mfma_acc(acc[1][nt], a[1][ks], b);
                }
            }
        }
        #pragma unroll
        for (int tt = 0; tt < 2; ++tt){
            float p0 = 0.f, p1 = 0.f, p2 = 0.f, p3 = 0.f;
            #pragma unroll
            for (int nt = 0; nt < 8; ++nt){
                float b = bfr[nt], wh = whr[nt];
                p0 += relu(acc[tt][nt][0]+b)*wh;
                p1 += relu(acc[tt][nt][1]+b)*wh;
                p2 += relu(acc[tt][nt][2]+b)*wh;
                p3 += relu(acc[tt][nt][3]+b)*wh;
            }
            #pragma unroll
            for (int m = 1; m < 16; m <<= 1){
                p0 += __shfl_xor(p0, m);
                p1 += __shfl_xor(p1, m);
                p2 += __shfl_xor(p2, m);
                p3 += __shfl_xor(p3, m);
            }
            if (l15 == 0){
                long long r = r0 + tt*16 + quad*4;
                if (r   < nrows) out[r  ] = p0 + bb;
                if (r+1 < nrows) out[r+1] = p1 + bb;
                if (r+2 < nrows) out[r+2] = p2 + bb;
                if (r+3 < nrows) out[r+3] = p3 + bb;
            }
        }
    }
}

// ================== fused small-level kernels (round-0 proven, R5/R8 config) =====

__global__ __launch_bounds__(256, 3) void up_f(
    const __bf16* __restrict__ wts,     // Ws @0, Wc @16384 (row-major)
    const float* __restrict__ init,
    const float* __restrict__ bs, const float* __restrict__ bc,
    __bf16* __restrict__ agg,
    long long child_base, long long parent_base, long long n_par)
{
    __shared__ __bf16 lds_w[128*LPAD];
    __shared__ __bf16 lds_sib[32*LPAD];

    const int t = threadIdx.x;
    const int w = t >> 6, lane = t & 63, quad = lane >> 4, l15 = lane & 15;

    load_w_lds(wts, lds_w, 128);                // Ws
    __syncthreads();

    const long long n_child = n_par * 8;
    const long long rowbase = (long long)blockIdx.x*128 + w*32;

    f32x4 acc[2][8];
    #pragma unroll
    for (int tt = 0; tt < 2; ++tt)
        #pragma unroll
        for (int i = 0; i < 8; ++i) acc[tt][i] = f32x4{0.f,0.f,0.f,0.f};

    bf16x8 af[2][4];
    #pragma unroll
    for (int tt = 0; tt < 2; ++tt){
        long long r = rowbase + tt*16 + l15;
        if (r >= n_child) r = n_child - 1;
        const long long base = (child_base + r)*DIM;
        #pragma unroll
        for (int ks = 0; ks < 4; ++ks)
            af[tt][ks] = *(const bf16x8*)(agg + base + ks*32 + quad*8);
    }
    #pragma unroll
    for (int ks = 0; ks < 4; ++ks){
        #pragma unroll
        for (int nt = 0; nt < 8; ++nt){
            bf16x8 bfrag = *(const bf16x8*)&lds_w[(nt*16 + l15)*LPAD + ks*32 + quad*8];
            mfma_acc(acc[0][nt], af[0][ks], bfrag);
            mfma_acc(acc[1][nt], af[1][ks], bfrag);
        }
    }
    #pragma unroll
    for (int tt = 0; tt < 2; ++tt){
        const int g = w*8 + tt*4 + quad;
        #pragma unroll
        for (int nt = 0; nt < 8; ++nt){
            int col = nt*16 + l15;
            float b = bs[col];
            float s = relu(acc[tt][nt][0]+b) + relu(acc[tt][nt][1]+b)
                    + relu(acc[tt][nt][2]+b) + relu(acc[tt][nt][3]+b);
            lds_sib[g*LPAD + col] = tobf(s * 0.25f);
        }
    }
    __syncthreads();
    load_w_lds(wts + 16384, lds_w, 128);        // Wc (reuse LDS)
    __syncthreads();

    if (w < 2){
        f32x4 a2c[8];
        #pragma unroll
        for (int i = 0; i < 8; ++i) a2c[i] = f32x4{0.f,0.f,0.f,0.f};
        bf16x8 a2[4];
        #pragma unroll
        for (int ks = 0; ks < 4; ++ks)
            a2[ks] = *(const bf16x8*)&lds_sib[(w*16 + l15)*LPAD + ks*32 + quad*8];
        #pragma unroll
        for (int ks = 0; ks < 4; ++ks){
            #pragma unroll
            for (int nt = 0; nt < 8; ++nt){
                bf16x8 bfrag = *(const bf16x8*)&lds_w[(nt*16 + l15)*LPAD + ks*32 + quad*8];
                mfma_acc(a2c[nt], a2[ks], bfrag);
            }
        }
        const long long p0 = (long long)blockIdx.x*16 + w*8 + quad*2;
        const long long p1 = p0 + 1;
        #pragma unroll
        for (int nt = 0; nt < 8; ++nt){
            int col = nt*16 + l15;
            float b = bc[col];
            float r0 = relu(a2c[nt][0]+b), r1 = relu(a2c[nt][1]+b);
            float r2 = relu(a2c[nt][2]+b), r3 = relu(a2c[nt][3]+b);
            if (p0 < n_par){
                long long gr = parent_base + p0;
                agg[gr*DIM + col] = tobf(init[gr*DIM + col] + 0.5f*(r0+r1));
            }
            if (p1 < n_par){
                long long gr = parent_base + p1;
                agg[gr*DIM + col] = tobf(init[gr*DIM + col] + 0.5f*(r2+r3));
            }
        }
    }
}

__global__ __launch_bounds__(256, 3) void down_f(
    const __bf16* __restrict__ wts,     // Wx @32768 (row-major)
    const float* __restrict__ bx,
    const __bf16* __restrict__ agg,
    __bf16* __restrict__ ctx,
    long long parent_base, long long child_base, long long n_par)
{
    __shared__ __bf16 lds_w[128*LPAD];
    __shared__ float lds_ctxh[16*132];

    const int t = threadIdx.x;
    const int w = t >> 6, lane = t & 63, quad = lane >> 4, l15 = lane & 15;

    load_w_lds(wts + 32768, lds_w, 128);        // Wx
    __syncthreads();

    const long long n_child = n_par*8;

    if (w == 0){
        f32x4 acc[8];
        #pragma unroll
        for (int i = 0; i < 8; ++i) acc[i] = f32x4{0.f,0.f,0.f,0.f};
        bf16x8 a[4];
        long long p = (long long)blockIdx.x*16 + l15;
        if (p >= n_par) p = n_par - 1;
        #pragma unroll
        for (int ks = 0; ks < 4; ++ks)
            a[ks] = *(const bf16x8*)(ctx + (parent_base + p)*DIM + ks*32 + quad*8);
        #pragma unroll
        for (int ks = 0; ks < 4; ++ks){
            #pragma unroll
            for (int nt = 0; nt < 8; ++nt){
                bf16x8 bfrag = *(const bf16x8*)&lds_w[(nt*16 + l15)*LPAD + ks*32 + quad*8];
                mfma_acc(acc[nt], a[ks], bfrag);
            }
        }
        #pragma unroll
        for (int nt = 0; nt < 8; ++nt){
            int col = nt*16 + l15;
            float b = bx[col];
            #pragma unroll
            for (int rg = 0; rg < 4; ++rg)
                lds_ctxh[(quad*4 + rg)*132 + col] = relu(acc[nt][rg] + b);
        }
    }
    __syncthreads();

    f32x4 acc[2][8];
    #pragma unroll
    for (int tt = 0; tt < 2; ++tt)
        #pragma unroll
        for (int i = 0; i < 8; ++i) acc[tt][i] = f32x4{0.f,0.f,0.f,0.f};
    bf16x8 a[2][4];
    const long long rowbase = (long long)blockIdx.x*128 + w*32;
    #pragma unroll
    for (int tt = 0; tt < 2; ++tt){
        long long r = rowbase + tt*16 + l15;
        if (r >= n_child) r = n_child - 1;
        #pragma unroll
        for (int ks = 0; ks < 4; ++ks)
            a[tt][ks] = *(const bf16x8*)(agg + (child_base + r)*DIM + ks*32 + quad*8);
    }
    #pragma unroll
    for (int ks = 0; ks < 4; ++ks){
        #pragma unroll
        for (int nt = 0; nt < 8; ++nt){
            bf16x8 bfrag = *(const bf16x8*)&lds_w[(nt*16 + l15)*LPAD + ks*32 + quad*8];
            mfma_acc(acc[0][nt], a[0][ks], bfrag);
            mfma_acc(acc[1][nt], a[1][ks], bfrag);
        }
    }
    #pragma unroll
    for (int tt = 0; tt < 2; ++tt){
        const long long rb = rowbase + tt*16 + quad*4;
        const int p_loc = w*4 + tt*2 + (quad >> 1);
        #pragma unroll
        for (int nt = 0; nt < 8; ++nt){
            int col = nt*16 + l15;
            float b = bx[col];
            float h0 = relu(acc[tt][nt][0]+b), h1 = relu(acc[tt][nt][1]+b);
            float h2 = relu(acc[tt][nt][2]+b), h3 = relu(acc[tt][nt][3]+b);
            float s = h0 + h1 + h2 + h3;
            float ch = lds_ctxh[p_loc*132 + col];
            if (rb   < n_child) ctx[(child_base + rb  )*DIM + col] = tobf((ch + s - h0)*0.25f);
            if (rb+1 < n_child) ctx[(child_base + rb+1)*DIM + col] = tobf((ch + s - h1)*0.25f);
            if (rb+2 < n_child) ctx[(child_base + rb+2)*DIM + col] = tobf((ch + s - h2)*0.25f);
            if (rb+3 < n_child) ctx[(child_base + rb+3)*DIM + col] = tobf((ch + s - h3)*0.25f);
        }
    }
}

extern "C" void kernel_launch(void* const* d_in, const int* in_sizes, int n_in,
                              void* d_out, int out_size, void* d_ws, size_t ws_size,
                              hipStream_t stream)
{
    const float* init = (const float*)d_in[0];
    const float* Ws  = (const float*)d_in[1];
    const float* bs  = (const float*)d_in[2];
    const float* Wc  = (const float*)d_in[3];
    const float* bc  = (const float*)d_in[4];
    const float* Wx  = (const float*)d_in[5];
    const float* bx  = (const float*)d_in[6];
    const float* Wf  = (const float*)d_in[7];
    const float* bff = (const float*)d_in[8];
    const float* Wh  = (const float*)d_in[9];
    const float* bh  = (const float*)d_in[10];
    float* out = (float*)d_out;

    // ws layout: agg bf16 [N,128] | ctx bf16 [N,128] | wts row-major (81920)
    //            | wfm frag-major (81920)
    __bf16* agg = (__bf16*)d_ws;
    __bf16* ctx = agg + NTOT*DIM;
    __bf16* wts = ctx + NTOT*DIM;
    __bf16* wfm = wts + 81920;

    static const long long SZ[7] = {1,8,64,512,4096,32768,262144};
    static const long long OF[8] = {0,1,9,73,585,4681,37449,299593};

    prep_kernel<<<dim3(641), dim3(256), 0, stream>>>(Ws, Wc, Wx, Wf, wts, ctx);

    // ---- up: leaf level barrier-free wave-fused; smaller levels round-0 fused ----
    upleaf_kernel<<<dim3(1024), dim3(256), 0, stream>>>(wfm, init, bs, bc, agg);
    for (int l = 4; l >= 0; --l){
        int blocks = (int)((SZ[l]*8 + 127)/128);
        up_f<<<dim3(blocks), dim3(256), 0, stream>>>(
            wts, init, bs, bc, agg, OF[l+1], OF[l], SZ[l]);
    }
    // ---- down: smaller levels round-0 fused (writes ctx rows 1..37448) ----
    for (int l = 0; l < 5; ++l){
        int blocks = (int)((SZ[l]*8 + 127)/128);
        down_f<<<dim3(blocks), dim3(256), 0, stream>>>(
            wts, bx, agg, ctx, OF[l], OF[l+1], SZ[l]);
    }
    // ---- leaf down-step fused with final head (leaf ctx/agg never hit HBM) ----
    downfinal_kernel<<<dim3(256), dim3(512), 0, stream>>>(
        wfm + 32768, wfm + 49152, bx, bff, Wh, bh, init, ctx, out);
    // ---- final head for the 37449 non-leaf rows ----
    final_nl_kernel<<<dim3(147), dim3(512), 0, stream>>>(
        wfm + 49152, ctx, agg, bff, Wh, bh, out, 37449LL);
}

// Round 11
// 400.391 us; speedup vs baseline: 1.6614x; 1.0215x over previous
//
#include <hip/hip_runtime.h>
#include <stdint.h>

#define DIM 128
#define LPAD 136   // padded LDS row stride for the fused small-level kernels (round-0 proven)

static constexpr long long NTOT = 299593LL;

using bf16x8 = __attribute__((ext_vector_type(8))) __bf16;
using f32x4  = __attribute__((ext_vector_type(4))) float;

__device__ __forceinline__ float relu(float x){ return x > 0.f ? x : 0.f; }
__device__ __forceinline__ __bf16 tobf(float x){ return (__bf16)x; }

__device__ __forceinline__ void mfma_acc(f32x4& acc, bf16x8 a, bf16x8 b){
    acc = __builtin_amdgcn_mfma_f32_16x16x32_bf16(a, b, acc, 0, 0, 0);
}

// XOR swizzle for a 16x128 bf16 LDS slice (16B-chunk granularity, bijective).
// Same function on write and read. (R3..R8-proven)
__device__ __forceinline__ int swz(int row, int col){
    return row*128 + (col ^ ((row & 7) << 3));
}

// copy 128x128 bf16 weight (row stride src_stride) into padded LDS (stride LPAD)
// -- used by the fused small-level kernels (round-0 proven)
__device__ __forceinline__ void load_w_lds(const __bf16* __restrict__ wsrc,
                                           __bf16* lds, int src_stride){
    int t = threadIdx.x;
    #pragma unroll
    for (int i = 0; i < 8; ++i){
        int idx = t + i*256;                 // 2048 chunks of 8 bf16
        int row = idx >> 4, col8 = (idx & 15) << 3;
        *(uint4*)(&lds[row*LPAD + col8]) = *(const uint4*)(wsrc + row*src_stride + col8);
    }
}

// ---- prep (R3/R5/R8-proven): weights fp32->bf16 in BOTH row-major (fused small
// kernels) and frag-major (leaf/final/tail kernels) layouts; root ctx = ones.
// Frag-major: element (r,c) -> ((nt*4+ks)*512 + lane*8 + j), nt=r>>4, l15=r&15,
// ks=c>>5, quad=(c>>3)&3, j=c&7, lane=quad*16+l15.
__global__ __launch_bounds__(256) void prep_kernel(
    const float* __restrict__ Ws, const float* __restrict__ Wc,
    const float* __restrict__ Wx, const float* __restrict__ Wf,
    __bf16* __restrict__ wts, __bf16* __restrict__ ctx)
{
    int idx = blockIdx.x*256 + threadIdx.x;
    if (idx < 81920){
        float v;
        if      (idx < 16384) v = Ws[idx];
        else if (idx < 32768) v = Wc[idx - 16384];
        else if (idx < 49152) v = Wx[idx - 32768];
        else                  v = Wf[idx - 49152];
        wts[idx] = tobf(v);
    } else if (idx < 163840){
        int d2 = idx - 81920;
        int sel = d2 >> 14;                 // 0:Ws 1:Wc 2:Wx 3:Wf-h0 4:Wf-h1
        int d   = d2 & 16383;
        int j = d & 7, ln = (d >> 3) & 63, f = d >> 9;
        int r = (f >> 2)*16 + (ln & 15);
        int c = (f & 3)*32 + (ln >> 4)*8 + j;
        float v;
        if      (sel == 0) v = Ws[r*128 + c];
        else if (sel == 1) v = Wc[r*128 + c];
        else if (sel == 2) v = Wx[r*128 + c];
        else if (sel == 3) v = Wf[r*256 + c];
        else               v = Wf[r*256 + 128 + c];
        wts[idx] = tobf(v);
    } else if (idx < 163968){
        ctx[idx - 163840] = tobf(1.0f);     // root context row
    }
}

// ================== per-level wave-task bodies (R4/R6/R7-correctness-proven) ==========

// up task: 64 children -> GEMM1(Ws)+sib-mean -> 16 sib rows in wave's LDS slice ->
// GEMM2(Wc) -> 8 parents, guarded. lds_w holds Ws @0 AND Wc @16384 (frag-major).
__device__ __forceinline__ void up_level_task(
    const __bf16* __restrict__ lds_w,
    __bf16* __restrict__ sib,
    const float* __restrict__ init,
    const float* __restrict__ bsr, const float* __restrict__ bcr,
    __bf16* __restrict__ agg,
    long long task, long long cb, long long pb, long long n_par,
    int lane, int quad, int l15)
{
    const long long n_child = n_par*8;
    const long long c0 = task*64;
    bf16x8 af[4][4];
    #pragma unroll
    for (int tt = 0; tt < 4; ++tt){
        long long r = c0 + tt*16 + l15;
        if (r >= n_child) r = n_child - 1;
        const __bf16* p = agg + (cb + r)*DIM + quad*8;
        #pragma unroll
        for (int ks = 0; ks < 4; ++ks)
            af[tt][ks] = *(const bf16x8*)(p + ks*32);
    }
    #pragma unroll
    for (int h = 0; h < 2; ++h){
        f32x4 acc[2][8];
        #pragma unroll
        for (int u = 0; u < 2; ++u)
            #pragma unroll
            for (int i = 0; i < 8; ++i) acc[u][i] = f32x4{0.f,0.f,0.f,0.f};
        #pragma unroll
        for (int ks = 0; ks < 4; ++ks){
            #pragma unroll
            for (int nt = 0; nt < 8; ++nt){
                bf16x8 b = *(const bf16x8*)&lds_w[((nt*4+ks)<<9) + lane*8];
                mfma_acc(acc[0][nt], af[2*h+0][ks], b);
                mfma_acc(acc[1][nt], af[2*h+1][ks], b);
            }
        }
        #pragma unroll
        for (int u = 0; u < 2; ++u){
            const int row = (2*h+u)*4 + quad;   // local sib row 0..15
            #pragma unroll
            for (int nt = 0; nt < 8; ++nt){
                float b = bsr[nt];
                float s = relu(acc[u][nt][0]+b) + relu(acc[u][nt][1]+b)
                        + relu(acc[u][nt][2]+b) + relu(acc[u][nt][3]+b);
                sib[swz(row, nt*16 + l15)] = tobf(s*0.25f);
            }
        }
    }
    bf16x8 a2[4];
    #pragma unroll
    for (int ks = 0; ks < 4; ++ks)
        a2[ks] = *(const bf16x8*)&sib[swz(l15, ks*32 + quad*8)];
    f32x4 ac2[8];
    #pragma unroll
    for (int i = 0; i < 8; ++i) ac2[i] = f32x4{0.f,0.f,0.f,0.f};
    #pragma unroll
    for (int ks = 0; ks < 4; ++ks){
        #pragma unroll
        for (int nt = 0; nt < 8; ++nt){
            bf16x8 b = *(const bf16x8*)&lds_w[16384 + ((nt*4+ks)<<9) + lane*8];
            mfma_acc(ac2[nt], a2[ks], b);
        }
    }
    const long long p0l = task*8 + quad*2, p1l = p0l + 1;
    #pragma unroll
    for (int nt = 0; nt < 8; ++nt){
        int col = nt*16 + l15;
        float b = bcr[nt];
        float r0_ = relu(ac2[nt][0]+b), r1_ = relu(ac2[nt][1]+b);
        float r2_ = relu(ac2[nt][2]+b), r3_ = relu(ac2[nt][3]+b);
        if (p0l < n_par){
            long long gr = pb + p0l;
            agg[gr*DIM + col] = tobf(init[gr*DIM + col] + 0.5f*(r0_+r1_));
        }
        if (p1l < n_par){
            long long gr = pb + p1l;
            agg[gr*DIM + col] = tobf(init[gr*DIM + col] + 0.5f*(r2_+r3_));
        }
    }
}

// down task: 16 parents -> ctxh in wave's LDS slice -> 8 child tiles, guarded.
__device__ __forceinline__ void down_level_task(
    const __bf16* __restrict__ lds_w,   // Wx frag-major
    __bf16* __restrict__ ch,
    const float* __restrict__ bxr,
    const __bf16* __restrict__ agg, __bf16* __restrict__ ctx,
    long long task, long long pb, long long cb, long long n_par,
    int lane, int quad, int l15)
{
    const long long n_child = n_par*8;
    {
        long long p = task*16 + l15;
        if (p >= n_par) p = n_par - 1;
        bf16x8 ap[4];
        #pragma unroll
        for (int ks = 0; ks < 4; ++ks)
            ap[ks] = *(const bf16x8*)(ctx + (pb + p)*DIM + ks*32 + quad*8);
        f32x4 acp[8];
        #pragma unroll
        for (int i = 0; i < 8; ++i) acp[i] = f32x4{0.f,0.f,0.f,0.f};
        #pragma unroll
        for (int ks = 0; ks < 4; ++ks){
            #pragma unroll
            for (int nt = 0; nt < 8; ++nt){
                bf16x8 b = *(const bf16x8*)&lds_w[((nt*4+ks)<<9) + lane*8];
                mfma_acc(acp[nt], ap[ks], b);
            }
        }
        #pragma unroll
        for (int nt = 0; nt < 8; ++nt){
            float b = bxr[nt];
            #pragma unroll
            for (int rg = 0; rg < 4; ++rg)
                ch[swz(quad*4 + rg, nt*16 + l15)] = tobf(relu(acp[nt][rg] + b));
        }
    }
    #pragma unroll 1
    for (int ct = 0; ct < 8; ++ct){
        const long long ch0 = task*128 + ct*16;
        if (ch0 >= n_child) break;
        bf16x8 a[4];
        {
            long long r = ch0 + l15;
            if (r >= n_child) r = n_child - 1;
            const __bf16* p = agg + (cb + r)*DIM + quad*8;
            #pragma unroll
            for (int ks = 0; ks < 4; ++ks)
                a[ks] = *(const bf16x8*)(p + ks*32);
        }
        f32x4 acc[8];
        #pragma unroll
        for (int i = 0; i < 8; ++i) acc[i] = f32x4{0.f,0.f,0.f,0.f};
        #pragma unroll
        for (int ks = 0; ks < 4; ++ks){
            #pragma unroll
            for (int nt = 0; nt < 8; ++nt){
                bf16x8 b = *(const bf16x8*)&lds_w[((nt*4+ks)<<9) + lane*8];
                mfma_acc(acc[nt], a[ks], b);
            }
        }
        const long long rb = ch0 + quad*4;
        const int p_loc = ct*2 + (quad >> 1);
        #pragma unroll
        for (int nt = 0; nt < 8; ++nt){
            int col = nt*16 + l15;
            float b = bxr[nt];
            float h0 = relu(acc[nt][0]+b), h1 = relu(acc[nt][1]+b);
            float h2 = relu(acc[nt][2]+b), h3 = relu(acc[nt][3]+b);
            float s = h0 + h1 + h2 + h3;
            float chv = (float)ch[swz(p_loc, col)];
            if (rb   < n_child) ctx[(cb + rb  )*DIM + col] = tobf((chv + s - h0)*0.25f);
            if (rb+1 < n_child) ctx[(cb + rb+1)*DIM + col] = tobf((chv + s - h1)*0.25f);
            if (rb+2 < n_child) ctx[(cb + rb+2)*DIM + col] = tobf((chv + s - h2)*0.25f);
            if (rb+3 < n_child) ctx[(cb + rb+3)*DIM + col] = tobf((chv + s - h3)*0.25f);
        }
    }
}

// ================== upleaf v3 (R8-proven, best): barrier-free, no leaf-agg store ======
__global__ __launch_bounds__(256, 2) void upleaf_kernel(
    const __bf16* __restrict__ wfm,     // Ws @0, Wc @16384 (frag-major)
    const float* __restrict__ init,
    const float* __restrict__ bs, const float* __restrict__ bc,
    __bf16* __restrict__ agg)
{
    __shared__ __attribute__((aligned(16))) __bf16 lds_w[32768];    // Ws | Wc
    __shared__ __attribute__((aligned(16))) __bf16 lds_sib[4*2048]; // per-wave 16x128
    {
        const int t = threadIdx.x;
        #pragma unroll
        for (int i = 0; i < 16; ++i){
            int c = i*256 + t;
            *((uint4*)lds_w + c) = *((const uint4*)wfm + c);
        }
    }
    __syncthreads();                        // the ONLY barrier

    const int t = threadIdx.x, w = t>>6, lane = t&63, quad = lane>>4, l15 = lane&15;
    const int sboff = w*2048;

    float bsr[8], bcr[8];
    #pragma unroll
    for (int nt = 0; nt < 8; ++nt){ bsr[nt] = bs[nt*16 + l15]; bcr[nt] = bc[nt*16 + l15]; }

    const long long gw = blockIdx.x*4 + w;  // 4096 waves, 64 rows each (exact)
    const long long r0 = gw*64;
    const long long cb = 37449LL;           // leaf base
    const long long pb = 4681LL + gw*8;     // this wave's 8 parents (global rows)

    const long long pr0 = pb + quad*2, pr1 = pr0 + 1;
    float pinit0[8], pinit1[8];
    #pragma unroll
    for (int nt = 0; nt < 8; ++nt){
        pinit0[nt] = init[pr0*DIM + nt*16 + l15];
        pinit1[nt] = init[pr1*DIM + nt*16 + l15];
    }

    bf16x8 af[4][4];
    #pragma unroll
    for (int tt = 0; tt < 4; ++tt){
        const long long base = (cb + r0 + tt*16 + l15)*DIM + quad*8;
        const float* p = init + base;
        #pragma unroll
        for (int ks = 0; ks < 4; ++ks){
            float4 v0 = *(const float4*)(p + ks*32);
            float4 v1 = *(const float4*)(p + ks*32 + 4);
            bf16x8 a;
            a[0]=tobf(v0.x); a[1]=tobf(v0.y); a[2]=tobf(v0.z); a[3]=tobf(v0.w);
            a[4]=tobf(v1.x); a[5]=tobf(v1.y); a[6]=tobf(v1.z); a[7]=tobf(v1.w);
            af[tt][ks] = a;                 // no leaf-agg store (R8 deletion)
        }
    }

    #pragma unroll
    for (int h = 0; h < 2; ++h){
        f32x4 acc[2][8];
        #pragma unroll
        for (int u = 0; u < 2; ++u)
            #pragma unroll
            for (int i = 0; i < 8; ++i) acc[u][i] = f32x4{0.f,0.f,0.f,0.f};
        #pragma unroll
        for (int ks = 0; ks < 4; ++ks){
            #pragma unroll
            for (int nt = 0; nt < 8; ++nt){
                bf16x8 b = *(const bf16x8*)&lds_w[((nt*4+ks)<<9) + lane*8];
                mfma_acc(acc[0][nt], af[2*h+0][ks], b);
                mfma_acc(acc[1][nt], af[2*h+1][ks], b);
            }
        }
        #pragma unroll
        for (int u = 0; u < 2; ++u){
            const int row = (2*h+u)*4 + quad;   // local sib row 0..15
            #pragma unroll
            for (int nt = 0; nt < 8; ++nt){
                float b = bsr[nt];
                float s = relu(acc[u][nt][0]+b) + relu(acc[u][nt][1]+b)
                        + relu(acc[u][nt][2]+b) + relu(acc[u][nt][3]+b);
                lds_sib[sboff + swz(row, nt*16 + l15)] = tobf(s*0.25f);
            }
        }
    }

    bf16x8 a2[4];
    #pragma unroll
    for (int ks = 0; ks < 4; ++ks)
        a2[ks] = *(const bf16x8*)&lds_sib[sboff + swz(l15, ks*32 + quad*8)];
    f32x4 ac2[8];
    #pragma unroll
    for (int i = 0; i < 8; ++i) ac2[i] = f32x4{0.f,0.f,0.f,0.f};
    #pragma unroll
    for (int ks = 0; ks < 4; ++ks){
        #pragma unroll
        for (int nt = 0; nt < 8; ++nt){
            bf16x8 b = *(const bf16x8*)&lds_w[16384 + ((nt*4+ks)<<9) + lane*8];
            mfma_acc(ac2[nt], a2[ks], b);
        }
    }
    #pragma unroll
    for (int nt = 0; nt < 8; ++nt){
        int col = nt*16 + l15;
        float b = bcr[nt];
        float r0_ = relu(ac2[nt][0]+b), r1_ = relu(ac2[nt][1]+b);
        float r2_ = relu(ac2[nt][2]+b), r3_ = relu(ac2[nt][3]+b);
        agg[pr0*DIM + col] = tobf(pinit0[nt] + 0.5f*(r0_+r1_));
        agg[pr1*DIM + col] = tobf(pinit1[nt] + 0.5f*(r2_+r3_));
    }
}

// ================== up_tail (R6-correctness-proven): levels 2,1,0 in ONE workgroup =====
__global__ __launch_bounds__(512, 2) void up_tail_kernel(
    const __bf16* __restrict__ wfm, const float* __restrict__ init,
    const float* __restrict__ bs, const float* __restrict__ bc,
    __bf16* __restrict__ agg)
{
    __shared__ __attribute__((aligned(16))) __bf16 lds_w[32768];
    __shared__ __attribute__((aligned(16))) __bf16 lds_sib[8*2048];
    {
        const int t = threadIdx.x;
        #pragma unroll
        for (int i = 0; i < 8; ++i)
            ((uint4*)lds_w)[i*512 + t] = ((const uint4*)wfm)[i*512 + t];
    }
    __syncthreads();
    const int t = threadIdx.x, w = t>>6, lane = t&63, quad = lane>>4, l15 = lane&15;
    float bsr[8], bcr[8];
    #pragma unroll
    for (int nt = 0; nt < 8; ++nt){ bsr[nt] = bs[nt*16 + l15]; bcr[nt] = bc[nt*16 + l15]; }
    __bf16* sib = lds_sib + w*2048;
    // level 2: 64 parents (8 tasks)
    if (w < 8) up_level_task(lds_w, sib, init, bsr, bcr, agg, w, 73, 9, 64, lane, quad, l15);
    __syncthreads();
    // level 1: 8 parents (1 task)
    if (w == 0) up_level_task(lds_w, sib, init, bsr, bcr, agg, 0, 9, 1, 8, lane, quad, l15);
    __syncthreads();
    // level 0: 1 parent (1 guarded task)
    if (w == 0) up_level_task(lds_w, sib, init, bsr, bcr, agg, 0, 1, 0, 1, lane, quad, l15);
}

// ================== down_tail (R6-correctness-proven): levels 0,1,2 in ONE workgroup ===
__global__ __launch_bounds__(512, 2) void down_tail_kernel(
    const __bf16* __restrict__ wfm,     // Wx frag-major
    const float* __restrict__ bx,
    const __bf16* __restrict__ agg, __bf16* __restrict__ ctx)
{
    __shared__ __attribute__((aligned(16))) __bf16 lds_w[16384];
    __shared__ __attribute__((aligned(16))) __bf16 lds_ch[8*2048];
    {
        const int t = threadIdx.x;
        #pragma unroll
        for (int i = 0; i < 4; ++i)
            ((uint4*)lds_w)[i*512 + t] = ((const uint4*)wfm)[i*512 + t];
    }
    __syncthreads();
    const int t = threadIdx.x, w = t>>6, lane = t&63, quad = lane>>4, l15 = lane&15;
    float bxr[8];
    #pragma unroll
    for (int nt = 0; nt < 8; ++nt) bxr[nt] = bx[nt*16 + l15];
    __bf16* ch = lds_ch + w*2048;
    // level 0: 1 parent (root, ctx=ones) -> 8 children
    if (w == 0) down_level_task(lds_w, ch, bxr, agg, ctx, 0, 0, 1, 1, lane, quad, l15);
    __syncthreads();
    // level 1: 8 parents -> 64 children
    if (w == 0) down_level_task(lds_w, ch, bxr, agg, ctx, 0, 1, 9, 8, lane, quad, l15);
    __syncthreads();
    // level 2: 64 parents -> 512 children (4 tasks)
    if (w < 4) down_level_task(lds_w, ch, bxr, agg, ctx, w, 9, 73, 64, lane, quad, l15);
}

// ================== downfinal v3 (R8-proven): leaf down+final head; A from init fp32 ==
__global__ __launch_bounds__(512, 2) void downfinal_kernel(
    const __bf16* __restrict__ wx,      // Wx frag-major
    const __bf16* __restrict__ wf,      // Wf frag-major [h0|h1]
    const float* __restrict__ bx, const float* __restrict__ bf_,
    const float* __restrict__ Wh, const float* __restrict__ bh,
    const float* __restrict__ init, const __bf16* __restrict__ ctx,
    float* __restrict__ out)
{
    __shared__ __attribute__((aligned(16))) __bf16 lds_wx[16384];
    __shared__ __attribute__((aligned(16))) __bf16 lds_wf[32768];
    __shared__ __attribute__((aligned(16))) __bf16 lds_st[8*2048];  // per-wave 16x128
    {
        const int t = threadIdx.x;
        #pragma unroll
        for (int i = 0; i < 4; ++i)
            ((uint4*)lds_wx)[i*512+t] = ((const uint4*)wx)[i*512+t];
        #pragma unroll
        for (int i = 0; i < 8; ++i)
            ((uint4*)lds_wf)[i*512+t] = ((const uint4*)wf)[i*512+t];
    }
    __syncthreads();                        // the ONLY barrier

    const int t = threadIdx.x, w = t>>6, lane = t&63, quad = lane>>4, l15 = lane&15;
    const int stoff = w*2048;
    const long long task = (long long)blockIdx.x*8 + w;     // 0..2047
    const long long cb = 37449LL;
    const long long pg = 4681LL + task*16;

    float bxr[8], bfr[8], whr[8];
    #pragma unroll
    for (int nt = 0; nt < 8; ++nt){
        bxr[nt] = bx[nt*16 + l15];
        bfr[nt] = bf_[nt*16 + l15];
        whr[nt] = Wh[nt*16 + l15];
    }
    const float bb = bh[0];

    // ctxh for this wave's 16 parents -> registers (chv[nt][rg], rows quad*4+rg)
    float chv[8][4];
    {
        bf16x8 ap[4];
        #pragma unroll
        for (int ks = 0; ks < 4; ++ks)
            ap[ks] = *(const bf16x8*)(ctx + (pg + l15)*DIM + ks*32 + quad*8);
        f32x4 acp[8];
        #pragma unroll
        for (int i = 0; i < 8; ++i) acp[i] = f32x4{0.f,0.f,0.f,0.f};
        #pragma unroll
        for (int ks = 0; ks < 4; ++ks){
            #pragma unroll
            for (int nt = 0; nt < 8; ++nt){
                bf16x8 b = *(const bf16x8*)&lds_wx[((nt*4+ks)<<9) + lane*8];
                mfma_acc(acp[nt], ap[ks], b);
            }
        }
        #pragma unroll
        for (int nt = 0; nt < 8; ++nt){
            #pragma unroll
            for (int rg = 0; rg < 4; ++rg)
                chv[nt][rg] = relu(acp[nt][rg] + bxr[nt]);
        }
    }

    // tile body: P = ct&1 (static chv reg indices); src lane = (ct>>1)*16 + l15
#define DF_TILE(CT, P, AF)                                                      \
    {                                                                           \
        f32x4 acch[8];                                                          \
        _Pragma("unroll") for (int i = 0; i < 8; ++i) acch[i] = f32x4{0.f,0.f,0.f,0.f}; \
        _Pragma("unroll") for (int ks = 0; ks < 4; ++ks){                       \
            _Pragma("unroll") for (int nt = 0; nt < 8; ++nt){                   \
                bf16x8 b = *(const bf16x8*)&lds_wx[((nt*4+ks)<<9) + lane*8];    \
                mfma_acc(acch[nt], AF[ks], b);                                  \
            }                                                                   \
        }                                                                       \
        const int srcl = ((CT)>>1)*16 + l15;                                    \
        _Pragma("unroll") for (int nt = 0; nt < 8; ++nt){                       \
            float vA = __shfl(chv[nt][2*(P)],   srcl);                          \
            float vB = __shfl(chv[nt][2*(P)+1], srcl);                          \
            float ch = (quad >= 2) ? vB : vA;                                   \
            float b = bxr[nt];                                                  \
            float h0 = relu(acch[nt][0]+b), h1 = relu(acch[nt][1]+b);           \
            float h2 = relu(acch[nt][2]+b), h3 = relu(acch[nt][3]+b);           \
            float s = h0+h1+h2+h3;                                              \
            int col = nt*16 + l15;                                              \
            lds_st[stoff + swz(quad*4+0, col)] = tobf((ch+s-h0)*0.25f);         \
            lds_st[stoff + swz(quad*4+1, col)] = tobf((ch+s-h1)*0.25f);         \
            lds_st[stoff + swz(quad*4+2, col)] = tobf((ch+s-h2)*0.25f);         \
            lds_st[stoff + swz(quad*4+3, col)] = tobf((ch+s-h3)*0.25f);         \
        }                                                                       \
        bf16x8 cf[4];                                                           \
        _Pragma("unroll") for (int ks = 0; ks < 4; ++ks)                        \
            cf[ks] = *(const bf16x8*)&lds_st[stoff + swz(l15, ks*32 + quad*8)]; \
        f32x4 accf[8];                                                          \
        _Pragma("unroll") for (int i = 0; i < 8; ++i) accf[i] = f32x4{0.f,0.f,0.f,0.f}; \
        _Pragma("unroll") for (int ks = 0; ks < 4; ++ks){                       \
            _Pragma("unroll") for (int nt = 0; nt < 8; ++nt){                   \
                bf16x8 b0 = *(const bf16x8*)&lds_wf[((nt*4+ks)<<9) + lane*8];           \
                bf16x8 b1 = *(const bf16x8*)&lds_wf[16384 + ((nt*4+ks)<<9) + lane*8];   \
                mfma_acc(accf[nt], cf[ks], b0);                                 \
                mfma_acc(accf[nt], AF[ks], b1);                                 \
            }                                                                   \
        }                                                                       \
        float p0=0.f,p1=0.f,p2=0.f,p3=0.f;                                      \
        _Pragma("unroll") for (int nt = 0; nt < 8; ++nt){                       \
            float b = bfr[nt], wh = whr[nt];                                    \
            p0 += relu(accf[nt][0]+b)*wh; p1 += relu(accf[nt][1]+b)*wh;         \
            p2 += relu(accf[nt][2]+b)*wh; p3 += relu(accf[nt][3]+b)*wh;         \
        }                                                                       \
        _Pragma("unroll") for (int m = 1; m < 16; m <<= 1){                     \
            p0 += __shfl_xor(p0, m); p1 += __shfl_xor(p1, m);                   \
            p2 += __shfl_xor(p2, m); p3 += __shfl_xor(p3, m);                   \
        }                                                                       \
        if (l15 == 0){                                                          \
            long long r = cb + task*128 + (long long)(CT)*16 + quad*4;          \
            out[r] = p0 + bb; out[r+1] = p1 + bb;                               \
            out[r+2] = p2 + bb; out[r+3] = p3 + bb;                             \
        }                                                                       \
    }

    auto LOADA = [&](bf16x8* d, int ct){
        const float* p = init + (cb + task*128 + ct*16 + l15)*DIM + quad*8;
        #pragma unroll
        for (int ks = 0; ks < 4; ++ks){
            float4 v0 = *(const float4*)(p + ks*32);
            float4 v1 = *(const float4*)(p + ks*32 + 4);
            bf16x8 a;
            a[0]=tobf(v0.x); a[1]=tobf(v0.y); a[2]=tobf(v0.z); a[3]=tobf(v0.w);
            a[4]=tobf(v1.x); a[5]=tobf(v1.y); a[6]=tobf(v1.z); a[7]=tobf(v1.w);
            d[ks] = a;
        }
    };

    bf16x8 aA[4], aB[4];
    LOADA(aA, 0);
    #pragma unroll 1
    for (int cp = 0; cp < 4; ++cp){
        const int ct0 = cp*2, ct1 = ct0 + 1;
        LOADA(aB, ct1);
        DF_TILE(ct0, 0, aA);
        if (cp < 3) LOADA(aA, ct0 + 2);
        DF_TILE(ct1, 1, aB);
    }
#undef DF_TILE
}

// ================== final for NON-LEAF rows only (R4..R8-proven, streaming) ==========
__global__ __launch_bounds__(512, 2) void final_nl_kernel(
    const __bf16* __restrict__ wfm,     // Wf frag-major, 2 halves x 16384
    const __bf16* __restrict__ ctx, const __bf16* __restrict__ agg,
    const float* __restrict__ bf_,
    const float* __restrict__ Wh, const float* __restrict__ bh,
    float* __restrict__ out, long long nrows)
{
    __shared__ __attribute__((aligned(16))) __bf16 lds_w[32768];
    {
        const int t = threadIdx.x;
        #pragma unroll
        for (int i = 0; i < 8; ++i){
            int c = i*512 + t;
            *((uint4*)lds_w + c) = *((const uint4*)wfm + c);
        }
    }
    __syncthreads();
    const int t = threadIdx.x, w = t>>6, lane = t&63, quad = lane>>4, l15 = lane&15;
    float bfr[8], whr[8];
    #pragma unroll
    for (int nt = 0; nt < 8; ++nt){
        bfr[nt] = bf_[nt*16 + l15];
        whr[nt] = Wh[nt*16 + l15];
    }
    const float bb = bh[0];
    const long long stride = (long long)gridDim.x*8;
    #pragma unroll 1
    for (long long tile = blockIdx.x*8 + w; ; tile += stride){
        const long long r0 = tile*32;
        if (r0 >= nrows) break;
        f32x4 acc[2][8];
        #pragma unroll
        for (int tt = 0; tt < 2; ++tt)
            #pragma unroll
            for (int i = 0; i < 8; ++i) acc[tt][i] = f32x4{0.f,0.f,0.f,0.f};
        #pragma unroll
        for (int half = 0; half < 2; ++half){
            const __bf16* src = half ? agg : ctx;
            bf16x8 a[2][4];
            #pragma unroll
            for (int tt = 0; tt < 2; ++tt){
                long long r = r0 + tt*16 + l15;
                if (r >= nrows) r = nrows - 1;
                #pragma unroll
                for (int ks = 0; ks < 4; ++ks)
                    a[tt][ks] = *(const bf16x8*)(src + r*DIM + ks*32 + quad*8);
            }
            #pragma unroll
            for (int ks = 0; ks < 4; ++ks){
                #pragma unroll
                for (int nt = 0; nt < 8; ++nt){
                    bf16x8 b = *(const bf16x8*)&lds_w[half*16384 + ((nt*4+ks)<<9) + lane*8];
                    mfma_acc(acc[0][nt], a[0][ks], b);
                    mfma_acc(acc[1][nt], a[1][ks], b);
                }
            }
        }
        #pragma unroll
        for (int tt = 0; tt < 2; ++tt){
            float p0 = 0.f, p1 = 0.f, p2 = 0.f, p3 = 0.f;
            #pragma unroll
            for (int nt = 0; nt < 8; ++nt){
                float b = bfr[nt], wh = whr[nt];
                p0 += relu(acc[tt][nt][0]+b)*wh;
                p1 += relu(acc[tt][nt][1]+b)*wh;
                p2 += relu(acc[tt][nt][2]+b)*wh;
                p3 += relu(acc[tt][nt][3]+b)*wh;
            }
            #pragma unroll
            for (int m = 1; m < 16; m <<= 1){
                p0 += __shfl_xor(p0, m);
                p1 += __shfl_xor(p1, m);
                p2 += __shfl_xor(p2, m);
                p3 += __shfl_xor(p3, m);
            }
            if (l15 == 0){
                long long r = r0 + tt*16 + quad*4;
                if (r   < nrows) out[r  ] = p0 + bb;
                if (r+1 < nrows) out[r+1] = p1 + bb;
                if (r+2 < nrows) out[r+2] = p2 + bb;
                if (r+3 < nrows) out[r+3] = p3 + bb;
            }
        }
    }
}

// ================== fused small-level kernels (round-0 proven; levels 3,4 only) =====

__global__ __launch_bounds__(256, 3) void up_f(
    const __bf16* __restrict__ wts,     // Ws @0, Wc @16384 (row-major)
    const float* __restrict__ init,
    const float* __restrict__ bs, const float* __restrict__ bc,
    __bf16* __restrict__ agg,
    long long child_base, long long parent_base, long long n_par)
{
    __shared__ __bf16 lds_w[128*LPAD];
    __shared__ __bf16 lds_sib[32*LPAD];

    const int t = threadIdx.x;
    const int w = t >> 6, lane = t & 63, quad = lane >> 4, l15 = lane & 15;

    load_w_lds(wts, lds_w, 128);                // Ws
    __syncthreads();

    const long long n_child = n_par * 8;
    const long long rowbase = (long long)blockIdx.x*128 + w*32;

    f32x4 acc[2][8];
    #pragma unroll
    for (int tt = 0; tt < 2; ++tt)
        #pragma unroll
        for (int i = 0; i < 8; ++i) acc[tt][i] = f32x4{0.f,0.f,0.f,0.f};

    bf16x8 af[2][4];
    #pragma unroll
    for (int tt = 0; tt < 2; ++tt){
        long long r = rowbase + tt*16 + l15;
        if (r >= n_child) r = n_child - 1;
        const long long base = (child_base + r)*DIM;
        #pragma unroll
        for (int ks = 0; ks < 4; ++ks)
            af[tt][ks] = *(const bf16x8*)(agg + base + ks*32 + quad*8);
    }
    #pragma unroll
    for (int ks = 0; ks < 4; ++ks){
        #pragma unroll
        for (int nt = 0; nt < 8; ++nt){
            bf16x8 bfrag = *(const bf16x8*)&lds_w[(nt*16 + l15)*LPAD + ks*32 + quad*8];
            mfma_acc(acc[0][nt], af[0][ks], bfrag);
            mfma_acc(acc[1][nt], af[1][ks], bfrag);
        }
    }
    #pragma unroll
    for (int tt = 0; tt < 2; ++tt){
        const int g = w*8 + tt*4 + quad;
        #pragma unroll
        for (int nt = 0; nt < 8; ++nt){
            int col = nt*16 + l15;
            float b = bs[col];
            float s = relu(acc[tt][nt][0]+b) + relu(acc[tt][nt][1]+b)
                    + relu(acc[tt][nt][2]+b) + relu(acc[tt][nt][3]+b);
            lds_sib[g*LPAD + col] = tobf(s * 0.25f);
        }
    }
    __syncthreads();
    load_w_lds(wts + 16384, lds_w, 128);        // Wc (reuse LDS)
    __syncthreads();

    if (w < 2){
        f32x4 a2c[8];
        #pragma unroll
        for (int i = 0; i < 8; ++i) a2c[i] = f32x4{0.f,0.f,0.f,0.f};
        bf16x8 a2[4];
        #pragma unroll
        for (int ks = 0; ks < 4; ++ks)
            a2[ks] = *(const bf16x8*)&lds_sib[(w*16 + l15)*LPAD + ks*32 + quad*8];
        #pragma unroll
        for (int ks = 0; ks < 4; ++ks){
            #pragma unroll
            for (int nt = 0; nt < 8; ++nt){
                bf16x8 bfrag = *(const bf16x8*)&lds_w[(nt*16 + l15)*LPAD + ks*32 + quad*8];
                mfma_acc(a2c[nt], a2[ks], bfrag);
            }
        }
        const long long p0 = (long long)blockIdx.x*16 + w*8 + quad*2;
        const long long p1 = p0 + 1;
        #pragma unroll
        for (int nt = 0; nt < 8; ++nt){
            int col = nt*16 + l15;
            float b = bc[col];
            float r0 = relu(a2c[nt][0]+b), r1 = relu(a2c[nt][1]+b);
            float r2 = relu(a2c[nt][2]+b), r3 = relu(a2c[nt][3]+b);
            if (p0 < n_par){
                long long gr = parent_base + p0;
                agg[gr*DIM + col] = tobf(init[gr*DIM + col] + 0.5f*(r0+r1));
            }
            if (p1 < n_par){
                long long gr = parent_base + p1;
                agg[gr*DIM + col] = tobf(init[gr*DIM + col] + 0.5f*(r2+r3));
            }
        }
    }
}

__global__ __launch_bounds__(256, 3) void down_f(
    const __bf16* __restrict__ wts,     // Wx @32768 (row-major)
    const float* __restrict__ bx,
    const __bf16* __restrict__ agg,
    __bf16* __restrict__ ctx,
    long long parent_base, long long child_base, long long n_par)
{
    __shared__ __bf16 lds_w[128*LPAD];
    __shared__ float lds_ctxh[16*132];

    const int t = threadIdx.x;
    const int w = t >> 6, lane = t & 63, quad = lane >> 4, l15 = lane & 15;

    load_w_lds(wts + 32768, lds_w, 128);        // Wx
    __syncthreads();

    const long long n_child = n_par*8;

    if (w == 0){
        f32x4 acc[8];
        #pragma unroll
        for (int i = 0; i < 8; ++i) acc[i] = f32x4{0.f,0.f,0.f,0.f};
        bf16x8 a[4];
        long long p = (long long)blockIdx.x*16 + l15;
        if (p >= n_par) p = n_par - 1;
        #pragma unroll
        for (int ks = 0; ks < 4; ++ks)
            a[ks] = *(const bf16x8*)(ctx + (parent_base + p)*DIM + ks*32 + quad*8);
        #pragma unroll
        for (int ks = 0; ks < 4; ++ks){
            #pragma unroll
            for (int nt = 0; nt < 8; ++nt){
                bf16x8 bfrag = *(const bf16x8*)&lds_w[(nt*16 + l15)*LPAD + ks*32 + quad*8];
                mfma_acc(acc[nt], a[ks], bfrag);
            }
        }
        #pragma unroll
        for (int nt = 0; nt < 8; ++nt){
            int col = nt*16 + l15;
            float b = bx[col];
            #pragma unroll
            for (int rg = 0; rg < 4; ++rg)
                lds_ctxh[(quad*4 + rg)*132 + col] = relu(acc[nt][rg] + b);
        }
    }
    __syncthreads();

    f32x4 acc[2][8];
    #pragma unroll
    for (int tt = 0; tt < 2; ++tt)
        #pragma unroll
        for (int i = 0; i < 8; ++i) acc[tt][i] = f32x4{0.f,0.f,0.f,0.f};
    bf16x8 a[2][4];
    const long long rowbase = (long long)blockIdx.x*128 + w*32;
    #pragma unroll
    for (int tt = 0; tt < 2; ++tt){
        long long r = rowbase + tt*16 + l15;
        if (r >= n_child) r = n_child - 1;
        #pragma unroll
        for (int ks = 0; ks < 4; ++ks)
            a[tt][ks] = *(const bf16x8*)(agg + (child_base + r)*DIM + ks*32 + quad*8);
    }
    #pragma unroll
    for (int ks = 0; ks < 4; ++ks){
        #pragma unroll
        for (int nt = 0; nt < 8; ++nt){
            bf16x8 bfrag = *(const bf16x8*)&lds_w[(nt*16 + l15)*LPAD + ks*32 + quad*8];
            mfma_acc(acc[0][nt], a[0][ks], bfrag);
            mfma_acc(acc[1][nt], a[1][ks], bfrag);
        }
    }
    #pragma unroll
    for (int tt = 0; tt < 2; ++tt){
        const long long rb = rowbase + tt*16 + quad*4;
        const int p_loc = w*4 + tt*2 + (quad >> 1);
        #pragma unroll
        for (int nt = 0; nt < 8; ++nt){
            int col = nt*16 + l15;
            float b = bx[col];
            float h0 = relu(acc[tt][nt][0]+b), h1 = relu(acc[tt][nt][1]+b);
            float h2 = relu(acc[tt][nt][2]+b), h3 = relu(acc[tt][nt][3]+b);
            float s = h0 + h1 + h2 + h3;
            float ch = lds_ctxh[p_loc*132 + col];
            if (rb   < n_child) ctx[(child_base + rb  )*DIM + col] = tobf((ch + s - h0)*0.25f);
            if (rb+1 < n_child) ctx[(child_base + rb+1)*DIM + col] = tobf((ch + s - h1)*0.25f);
            if (rb+2 < n_child) ctx[(child_base + rb+2)*DIM + col] = tobf((ch + s - h2)*0.25f);
            if (rb+3 < n_child) ctx[(child_base + rb+3)*DIM + col] = tobf((ch + s - h3)*0.25f);
        }
    }
}

extern "C" void kernel_launch(void* const* d_in, const int* in_sizes, int n_in,
                              void* d_out, int out_size, void* d_ws, size_t ws_size,
                              hipStream_t stream)
{
    const float* init = (const float*)d_in[0];
    const float* Ws  = (const float*)d_in[1];
    const float* bs  = (const float*)d_in[2];
    const float* Wc  = (const float*)d_in[3];
    const float* bc  = (const float*)d_in[4];
    const float* Wx  = (const float*)d_in[5];
    const float* bx  = (const float*)d_in[6];
    const float* Wf  = (const float*)d_in[7];
    const float* bff = (const float*)d_in[8];
    const float* Wh  = (const float*)d_in[9];
    const float* bh  = (const float*)d_in[10];
    float* out = (float*)d_out;

    // ws layout: agg bf16 [N,128] | ctx bf16 [N,128] | wts row-major (81920)
    //            | wfm frag-major (81920)
    __bf16* agg = (__bf16*)d_ws;
    __bf16* ctx = agg + NTOT*DIM;
    __bf16* wts = ctx + NTOT*DIM;
    __bf16* wfm = wts + 81920;

    prep_kernel<<<dim3(641), dim3(256), 0, stream>>>(Ws, Wc, Wx, Wf, wts, ctx);

    // ---- up: leaf (level 5) barrier-free; levels 4,3 round-0 fused; 2..0 one WG ----
    upleaf_kernel<<<dim3(1024), dim3(256), 0, stream>>>(wfm, init, bs, bc, agg);
    up_f<<<dim3(256), dim3(256), 0, stream>>>(wts, init, bs, bc, agg,
                                              4681LL, 585LL, 4096LL);   // level 4
    up_f<<<dim3(32), dim3(256), 0, stream>>>(wts, init, bs, bc, agg,
                                             585LL, 73LL, 512LL);       // level 3
    up_tail_kernel<<<dim3(1), dim3(512), 0, stream>>>(wfm, init, bs, bc, agg); // 2,1,0

    // ---- down: levels 0..2 one WG; levels 3,4 round-0 fused; leaf fused w/ final ----
    down_tail_kernel<<<dim3(1), dim3(512), 0, stream>>>(wfm + 32768, bx, agg, ctx);
    down_f<<<dim3(32), dim3(256), 0, stream>>>(wts, bx, agg, ctx,
                                               73LL, 585LL, 512LL);     // level 3
    down_f<<<dim3(256), dim3(256), 0, stream>>>(wts, bx, agg, ctx,
                                                585LL, 4681LL, 4096LL); // level 4
    downfinal_kernel<<<dim3(256), dim3(512), 0, stream>>>(
        wfm + 32768, wfm + 49152, bx, bff, Wh, bh, init, ctx, out);
    final_nl_kernel<<<dim3(147), dim3(512), 0, stream>>>(
        wfm + 49152, ctx, agg, bff, Wh, bh, out, 37449LL);
}

// Round 12
// 362.291 us; speedup vs baseline: 1.8361x; 1.1052x over previous
//
#include <hip/hip_runtime.h>
#include <stdint.h>

#define DIM 128
#define LPAD 136   // padded LDS row stride for the fused small-level kernels (round-0 proven)

static constexpr long long NTOT = 299593LL;

using bf16x8 = __attribute__((ext_vector_type(8))) __bf16;
using f32x4  = __attribute__((ext_vector_type(4))) float;

__device__ __forceinline__ float relu(float x){ return x > 0.f ? x : 0.f; }
__device__ __forceinline__ __bf16 tobf(float x){ return (__bf16)x; }

__device__ __forceinline__ void mfma_acc(f32x4& acc, bf16x8 a, bf16x8 b){
    acc = __builtin_amdgcn_mfma_f32_16x16x32_bf16(a, b, acc, 0, 0, 0);
}

// XOR swizzle for a 16x128 bf16 LDS slice (16B-chunk granularity, bijective).
// Same function on write and read. (R3..R11-proven)
__device__ __forceinline__ int swz(int row, int col){
    return row*128 + (col ^ ((row & 7) << 3));
}

// copy 128x128 bf16 weight (row stride src_stride) into padded LDS (stride LPAD)
// -- used by the fused small-level kernels (round-0 proven)
__device__ __forceinline__ void load_w_lds(const __bf16* __restrict__ wsrc,
                                           __bf16* lds, int src_stride){
    int t = threadIdx.x;
    #pragma unroll
    for (int i = 0; i < 8; ++i){
        int idx = t + i*256;                 // 2048 chunks of 8 bf16
        int row = idx >> 4, col8 = (idx & 15) << 3;
        *(uint4*)(&lds[row*LPAD + col8]) = *(const uint4*)(wsrc + row*src_stride + col8);
    }
}

// ---- prep (R3..R11-proven): weights fp32->bf16 in BOTH row-major (fused small
// kernels) and frag-major (leaf/final/tail kernels) layouts; root ctx = ones.
// Frag-major: element (r,c) -> ((nt*4+ks)*512 + lane*8 + j), nt=r>>4, l15=r&15,
// ks=c>>5, quad=(c>>3)&3, j=c&7, lane=quad*16+l15.
__global__ __launch_bounds__(256) void prep_kernel(
    const float* __restrict__ Ws, const float* __restrict__ Wc,
    const float* __restrict__ Wx, const float* __restrict__ Wf,
    __bf16* __restrict__ wts, __bf16* __restrict__ ctx)
{
    int idx = blockIdx.x*256 + threadIdx.x;
    if (idx < 81920){
        float v;
        if      (idx < 16384) v = Ws[idx];
        else if (idx < 32768) v = Wc[idx - 16384];
        else if (idx < 49152) v = Wx[idx - 32768];
        else                  v = Wf[idx - 49152];
        wts[idx] = tobf(v);
    } else if (idx < 163840){
        int d2 = idx - 81920;
        int sel = d2 >> 14;                 // 0:Ws 1:Wc 2:Wx 3:Wf-h0 4:Wf-h1
        int d   = d2 & 16383;
        int j = d & 7, ln = (d >> 3) & 63, f = d >> 9;
        int r = (f >> 2)*16 + (ln & 15);
        int c = (f & 3)*32 + (ln >> 4)*8 + j;
        float v;
        if      (sel == 0) v = Ws[r*128 + c];
        else if (sel == 1) v = Wc[r*128 + c];
        else if (sel == 2) v = Wx[r*128 + c];
        else if (sel == 3) v = Wf[r*256 + c];
        else               v = Wf[r*256 + 128 + c];
        wts[idx] = tobf(v);
    } else if (idx < 163968){
        ctx[idx - 163840] = tobf(1.0f);     // root context row
    }
}

// ================== per-level wave-task bodies (R4/R6/R11-correctness-proven) ==========

// up task: 64 children -> GEMM1(Ws)+sib-mean -> 16 sib rows in wave's LDS slice ->
// GEMM2(Wc) -> 8 parents, guarded. lds_w holds Ws @0 AND Wc @16384 (frag-major).
__device__ __forceinline__ void up_level_task(
    const __bf16* __restrict__ lds_w,
    __bf16* __restrict__ sib,
    const float* __restrict__ init,
    const float* __restrict__ bsr, const float* __restrict__ bcr,
    __bf16* __restrict__ agg,
    long long task, long long cb, long long pb, long long n_par,
    int lane, int quad, int l15)
{
    const long long n_child = n_par*8;
    const long long c0 = task*64;
    bf16x8 af[4][4];
    #pragma unroll
    for (int tt = 0; tt < 4; ++tt){
        long long r = c0 + tt*16 + l15;
        if (r >= n_child) r = n_child - 1;
        const __bf16* p = agg + (cb + r)*DIM + quad*8;
        #pragma unroll
        for (int ks = 0; ks < 4; ++ks)
            af[tt][ks] = *(const bf16x8*)(p + ks*32);
    }
    #pragma unroll
    for (int h = 0; h < 2; ++h){
        f32x4 acc[2][8];
        #pragma unroll
        for (int u = 0; u < 2; ++u)
            #pragma unroll
            for (int i = 0; i < 8; ++i) acc[u][i] = f32x4{0.f,0.f,0.f,0.f};
        #pragma unroll
        for (int ks = 0; ks < 4; ++ks){
            #pragma unroll
            for (int nt = 0; nt < 8; ++nt){
                bf16x8 b = *(const bf16x8*)&lds_w[((nt*4+ks)<<9) + lane*8];
                mfma_acc(acc[0][nt], af[2*h+0][ks], b);
                mfma_acc(acc[1][nt], af[2*h+1][ks], b);
            }
        }
        #pragma unroll
        for (int u = 0; u < 2; ++u){
            const int row = (2*h+u)*4 + quad;   // local sib row 0..15
            #pragma unroll
            for (int nt = 0; nt < 8; ++nt){
                float b = bsr[nt];
                float s = relu(acc[u][nt][0]+b) + relu(acc[u][nt][1]+b)
                        + relu(acc[u][nt][2]+b) + relu(acc[u][nt][3]+b);
                sib[swz(row, nt*16 + l15)] = tobf(s*0.25f);
            }
        }
    }
    bf16x8 a2[4];
    #pragma unroll
    for (int ks = 0; ks < 4; ++ks)
        a2[ks] = *(const bf16x8*)&sib[swz(l15, ks*32 + quad*8)];
    f32x4 ac2[8];
    #pragma unroll
    for (int i = 0; i < 8; ++i) ac2[i] = f32x4{0.f,0.f,0.f,0.f};
    #pragma unroll
    for (int ks = 0; ks < 4; ++ks){
        #pragma unroll
        for (int nt = 0; nt < 8; ++nt){
            bf16x8 b = *(const bf16x8*)&lds_w[16384 + ((nt*4+ks)<<9) + lane*8];
            mfma_acc(ac2[nt], a2[ks], b);
        }
    }
    const long long p0l = task*8 + quad*2, p1l = p0l + 1;
    #pragma unroll
    for (int nt = 0; nt < 8; ++nt){
        int col = nt*16 + l15;
        float b = bcr[nt];
        float r0_ = relu(ac2[nt][0]+b), r1_ = relu(ac2[nt][1]+b);
        float r2_ = relu(ac2[nt][2]+b), r3_ = relu(ac2[nt][3]+b);
        if (p0l < n_par){
            long long gr = pb + p0l;
            agg[gr*DIM + col] = tobf(init[gr*DIM + col] + 0.5f*(r0_+r1_));
        }
        if (p1l < n_par){
            long long gr = pb + p1l;
            agg[gr*DIM + col] = tobf(init[gr*DIM + col] + 0.5f*(r2_+r3_));
        }
    }
}

// down task: 16 parents -> ctxh in wave's LDS slice -> 8 child tiles, guarded.
__device__ __forceinline__ void down_level_task(
    const __bf16* __restrict__ lds_w,   // Wx frag-major
    __bf16* __restrict__ ch,
    const float* __restrict__ bxr,
    const __bf16* __restrict__ agg, __bf16* __restrict__ ctx,
    long long task, long long pb, long long cb, long long n_par,
    int lane, int quad, int l15)
{
    const long long n_child = n_par*8;
    {
        long long p = task*16 + l15;
        if (p >= n_par) p = n_par - 1;
        bf16x8 ap[4];
        #pragma unroll
        for (int ks = 0; ks < 4; ++ks)
            ap[ks] = *(const bf16x8*)(ctx + (pb + p)*DIM + ks*32 + quad*8);
        f32x4 acp[8];
        #pragma unroll
        for (int i = 0; i < 8; ++i) acp[i] = f32x4{0.f,0.f,0.f,0.f};
        #pragma unroll
        for (int ks = 0; ks < 4; ++ks){
            #pragma unroll
            for (int nt = 0; nt < 8; ++nt){
                bf16x8 b = *(const bf16x8*)&lds_w[((nt*4+ks)<<9) + lane*8];
                mfma_acc(acp[nt], ap[ks], b);
            }
        }
        #pragma unroll
        for (int nt = 0; nt < 8; ++nt){
            float b = bxr[nt];
            #pragma unroll
            for (int rg = 0; rg < 4; ++rg)
                ch[swz(quad*4 + rg, nt*16 + l15)] = tobf(relu(acp[nt][rg] + b));
        }
    }
    #pragma unroll 1
    for (int ct = 0; ct < 8; ++ct){
        const long long ch0 = task*128 + ct*16;
        if (ch0 >= n_child) break;
        bf16x8 a[4];
        {
            long long r = ch0 + l15;
            if (r >= n_child) r = n_child - 1;
            const __bf16* p = agg + (cb + r)*DIM + quad*8;
            #pragma unroll
            for (int ks = 0; ks < 4; ++ks)
                a[ks] = *(const bf16x8*)(p + ks*32);
        }
        f32x4 acc[8];
        #pragma unroll
        for (int i = 0; i < 8; ++i) acc[i] = f32x4{0.f,0.f,0.f,0.f};
        #pragma unroll
        for (int ks = 0; ks < 4; ++ks){
            #pragma unroll
            for (int nt = 0; nt < 8; ++nt){
                bf16x8 b = *(const bf16x8*)&lds_w[((nt*4+ks)<<9) + lane*8];
                mfma_acc(acc[nt], a[ks], b);
            }
        }
        const long long rb = ch0 + quad*4;
        const int p_loc = ct*2 + (quad >> 1);
        #pragma unroll
        for (int nt = 0; nt < 8; ++nt){
            int col = nt*16 + l15;
            float b = bxr[nt];
            float h0 = relu(acc[nt][0]+b), h1 = relu(acc[nt][1]+b);
            float h2 = relu(acc[nt][2]+b), h3 = relu(acc[nt][3]+b);
            float s = h0 + h1 + h2 + h3;
            float chv = (float)ch[swz(p_loc, col)];
            if (rb   < n_child) ctx[(cb + rb  )*DIM + col] = tobf((chv + s - h0)*0.25f);
            if (rb+1 < n_child) ctx[(cb + rb+1)*DIM + col] = tobf((chv + s - h1)*0.25f);
            if (rb+2 < n_child) ctx[(cb + rb+2)*DIM + col] = tobf((chv + s - h2)*0.25f);
            if (rb+3 < n_child) ctx[(cb + rb+3)*DIM + col] = tobf((chv + s - h3)*0.25f);
        }
    }
}

// ================== upleaf v3 (R8/R11-proven, best): barrier-free, no leaf-agg store ==
__global__ __launch_bounds__(256, 2) void upleaf_kernel(
    const __bf16* __restrict__ wfm,     // Ws @0, Wc @16384 (frag-major)
    const float* __restrict__ init,
    const float* __restrict__ bs, const float* __restrict__ bc,
    __bf16* __restrict__ agg)
{
    __shared__ __attribute__((aligned(16))) __bf16 lds_w[32768];    // Ws | Wc
    __shared__ __attribute__((aligned(16))) __bf16 lds_sib[4*2048]; // per-wave 16x128
    {
        const int t = threadIdx.x;
        #pragma unroll
        for (int i = 0; i < 16; ++i){
            int c = i*256 + t;
            *((uint4*)lds_w + c) = *((const uint4*)wfm + c);
        }
    }
    __syncthreads();                        // the ONLY barrier

    const int t = threadIdx.x, w = t>>6, lane = t&63, quad = lane>>4, l15 = lane&15;
    const int sboff = w*2048;

    float bsr[8], bcr[8];
    #pragma unroll
    for (int nt = 0; nt < 8; ++nt){ bsr[nt] = bs[nt*16 + l15]; bcr[nt] = bc[nt*16 + l15]; }

    const long long gw = blockIdx.x*4 + w;  // 4096 waves, 64 rows each (exact)
    const long long r0 = gw*64;
    const long long cb = 37449LL;           // leaf base
    const long long pb = 4681LL + gw*8;     // this wave's 8 parents (global rows)

    const long long pr0 = pb + quad*2, pr1 = pr0 + 1;
    float pinit0[8], pinit1[8];
    #pragma unroll
    for (int nt = 0; nt < 8; ++nt){
        pinit0[nt] = init[pr0*DIM + nt*16 + l15];
        pinit1[nt] = init[pr1*DIM + nt*16 + l15];
    }

    bf16x8 af[4][4];
    #pragma unroll
    for (int tt = 0; tt < 4; ++tt){
        const long long base = (cb + r0 + tt*16 + l15)*DIM + quad*8;
        const float* p = init + base;
        #pragma unroll
        for (int ks = 0; ks < 4; ++ks){
            float4 v0 = *(const float4*)(p + ks*32);
            float4 v1 = *(const float4*)(p + ks*32 + 4);
            bf16x8 a;
            a[0]=tobf(v0.x); a[1]=tobf(v0.y); a[2]=tobf(v0.z); a[3]=tobf(v0.w);
            a[4]=tobf(v1.x); a[5]=tobf(v1.y); a[6]=tobf(v1.z); a[7]=tobf(v1.w);
            af[tt][ks] = a;                 // no leaf-agg store (R8 deletion)
        }
    }

    #pragma unroll
    for (int h = 0; h < 2; ++h){
        f32x4 acc[2][8];
        #pragma unroll
        for (int u = 0; u < 2; ++u)
            #pragma unroll
            for (int i = 0; i < 8; ++i) acc[u][i] = f32x4{0.f,0.f,0.f,0.f};
        #pragma unroll
        for (int ks = 0; ks < 4; ++ks){
            #pragma unroll
            for (int nt = 0; nt < 8; ++nt){
                bf16x8 b = *(const bf16x8*)&lds_w[((nt*4+ks)<<9) + lane*8];
                mfma_acc(acc[0][nt], af[2*h+0][ks], b);
                mfma_acc(acc[1][nt], af[2*h+1][ks], b);
            }
        }
        #pragma unroll
        for (int u = 0; u < 2; ++u){
            const int row = (2*h+u)*4 + quad;   // local sib row 0..15
            #pragma unroll
            for (int nt = 0; nt < 8; ++nt){
                float b = bsr[nt];
                float s = relu(acc[u][nt][0]+b) + relu(acc[u][nt][1]+b)
                        + relu(acc[u][nt][2]+b) + relu(acc[u][nt][3]+b);
                lds_sib[sboff + swz(row, nt*16 + l15)] = tobf(s*0.25f);
            }
        }
    }

    bf16x8 a2[4];
    #pragma unroll
    for (int ks = 0; ks < 4; ++ks)
        a2[ks] = *(const bf16x8*)&lds_sib[sboff + swz(l15, ks*32 + quad*8)];
    f32x4 ac2[8];
    #pragma unroll
    for (int i = 0; i < 8; ++i) ac2[i] = f32x4{0.f,0.f,0.f,0.f};
    #pragma unroll
    for (int ks = 0; ks < 4; ++ks){
        #pragma unroll
        for (int nt = 0; nt < 8; ++nt){
            bf16x8 b = *(const bf16x8*)&lds_w[16384 + ((nt*4+ks)<<9) + lane*8];
            mfma_acc(ac2[nt], a2[ks], b);
        }
    }
    #pragma unroll
    for (int nt = 0; nt < 8; ++nt){
        int col = nt*16 + l15;
        float b = bcr[nt];
        float r0_ = relu(ac2[nt][0]+b), r1_ = relu(ac2[nt][1]+b);
        float r2_ = relu(ac2[nt][2]+b), r3_ = relu(ac2[nt][3]+b);
        agg[pr0*DIM + col] = tobf(pinit0[nt] + 0.5f*(r0_+r1_));
        agg[pr1*DIM + col] = tobf(pinit1[nt] + 0.5f*(r2_+r3_));
    }
}

// ================== tails: up levels 2,1,0 AND down levels 0,1,2 in ONE workgroup =====
// Stages Ws|Wc (64KB) + Wx (32KB) once; __syncthreads is the level barrier (single WG).
__global__ __launch_bounds__(512, 2) void tails_kernel(
    const __bf16* __restrict__ wfm_up,  // Ws|Wc frag-major
    const __bf16* __restrict__ wfm_dn,  // Wx frag-major
    const float* __restrict__ init,
    const float* __restrict__ bs, const float* __restrict__ bc,
    const float* __restrict__ bx,
    __bf16* __restrict__ agg, __bf16* __restrict__ ctx)
{
    __shared__ __attribute__((aligned(16))) __bf16 lds_wu[32768];   // Ws | Wc
    __shared__ __attribute__((aligned(16))) __bf16 lds_wd[16384];   // Wx
    __shared__ __attribute__((aligned(16))) __bf16 lds_sl[8*2048];  // per-wave slices
    {
        const int t = threadIdx.x;
        #pragma unroll
        for (int i = 0; i < 8; ++i)
            ((uint4*)lds_wu)[i*512 + t] = ((const uint4*)wfm_up)[i*512 + t];
        #pragma unroll
        for (int i = 0; i < 4; ++i)
            ((uint4*)lds_wd)[i*512 + t] = ((const uint4*)wfm_dn)[i*512 + t];
    }
    __syncthreads();
    const int t = threadIdx.x, w = t>>6, lane = t&63, quad = lane>>4, l15 = lane&15;
    float bsr[8], bcr[8], bxr[8];
    #pragma unroll
    for (int nt = 0; nt < 8; ++nt){
        bsr[nt] = bs[nt*16 + l15]; bcr[nt] = bc[nt*16 + l15]; bxr[nt] = bx[nt*16 + l15];
    }
    __bf16* sl = lds_sl + w*2048;
    // up level 2: 64 parents (8 tasks)
    if (w < 8) up_level_task(lds_wu, sl, init, bsr, bcr, agg, w, 73, 9, 64, lane, quad, l15);
    __syncthreads();
    // up level 1: 8 parents
    if (w == 0) up_level_task(lds_wu, sl, init, bsr, bcr, agg, 0, 9, 1, 8, lane, quad, l15);
    __syncthreads();
    // up level 0: 1 parent (guarded)
    if (w == 0) up_level_task(lds_wu, sl, init, bsr, bcr, agg, 0, 1, 0, 1, lane, quad, l15);
    __syncthreads();
    // down level 0: root -> 8 children
    if (w == 0) down_level_task(lds_wd, sl, bxr, agg, ctx, 0, 0, 1, 1, lane, quad, l15);
    __syncthreads();
    // down level 1: 8 parents -> 64 children
    if (w == 0) down_level_task(lds_wd, sl, bxr, agg, ctx, 0, 1, 9, 8, lane, quad, l15);
    __syncthreads();
    // down level 2: 64 parents -> 512 children (4 tasks)
    if (w < 4) down_level_task(lds_wd, sl, bxr, agg, ctx, w, 9, 73, 64, lane, quad, l15);
}

// ================== downfinal v5: leaf down+final head + FUSED non-leaf final ==========
// R8/R11 body; after the 8 leaf tiles, each wave takes one non-leaf final tile
// (1171 tiles over 2048 wave-slots) reusing the still-valid lds_wf. No extra barrier.
__global__ __launch_bounds__(512, 2) void downfinal_kernel(
    const __bf16* __restrict__ wx,      // Wx frag-major
    const __bf16* __restrict__ wf,      // Wf frag-major [h0|h1]
    const float* __restrict__ bx, const float* __restrict__ bf_,
    const float* __restrict__ Wh, const float* __restrict__ bh,
    const float* __restrict__ init, const __bf16* __restrict__ ctx,
    const __bf16* __restrict__ agg, float* __restrict__ out)
{
    __shared__ __attribute__((aligned(16))) __bf16 lds_wx[16384];
    __shared__ __attribute__((aligned(16))) __bf16 lds_wf[32768];
    __shared__ __attribute__((aligned(16))) __bf16 lds_st[8*2048];  // per-wave 16x128
    {
        const int t = threadIdx.x;
        #pragma unroll
        for (int i = 0; i < 4; ++i)
            ((uint4*)lds_wx)[i*512+t] = ((const uint4*)wx)[i*512+t];
        #pragma unroll
        for (int i = 0; i < 8; ++i)
            ((uint4*)lds_wf)[i*512+t] = ((const uint4*)wf)[i*512+t];
    }
    __syncthreads();                        // the ONLY barrier

    const int t = threadIdx.x, w = t>>6, lane = t&63, quad = lane>>4, l15 = lane&15;
    const int stoff = w*2048;
    const long long task = (long long)blockIdx.x*8 + w;     // 0..2047
    const long long cb = 37449LL;
    const long long pg = 4681LL + task*16;

    float bxr[8], bfr[8], whr[8];
    #pragma unroll
    for (int nt = 0; nt < 8; ++nt){
        bxr[nt] = bx[nt*16 + l15];
        bfr[nt] = bf_[nt*16 + l15];
        whr[nt] = Wh[nt*16 + l15];
    }
    const float bb = bh[0];

    // ctxh for this wave's 16 parents -> registers (chv[nt][rg], rows quad*4+rg)
    float chv[8][4];
    {
        bf16x8 ap[4];
        #pragma unroll
        for (int ks = 0; ks < 4; ++ks)
            ap[ks] = *(const bf16x8*)(ctx + (pg + l15)*DIM + ks*32 + quad*8);
        f32x4 acp[8];
        #pragma unroll
        for (int i = 0; i < 8; ++i) acp[i] = f32x4{0.f,0.f,0.f,0.f};
        #pragma unroll
        for (int ks = 0; ks < 4; ++ks){
            #pragma unroll
            for (int nt = 0; nt < 8; ++nt){
                bf16x8 b = *(const bf16x8*)&lds_wx[((nt*4+ks)<<9) + lane*8];
                mfma_acc(acp[nt], ap[ks], b);
            }
        }
        #pragma unroll
        for (int nt = 0; nt < 8; ++nt){
            #pragma unroll
            for (int rg = 0; rg < 4; ++rg)
                chv[nt][rg] = relu(acp[nt][rg] + bxr[nt]);
        }
    }

    // tile body: P = ct&1 (static chv reg indices); src lane = (ct>>1)*16 + l15
#define DF_TILE(CT, P, AF)                                                      \
    {                                                                           \
        f32x4 acch[8];                                                          \
        _Pragma("unroll") for (int i = 0; i < 8; ++i) acch[i] = f32x4{0.f,0.f,0.f,0.f}; \
        _Pragma("unroll") for (int ks = 0; ks < 4; ++ks){                       \
            _Pragma("unroll") for (int nt = 0; nt < 8; ++nt){                   \
                bf16x8 b = *(const bf16x8*)&lds_wx[((nt*4+ks)<<9) + lane*8];    \
                mfma_acc(acch[nt], AF[ks], b);                                  \
            }                                                                   \
        }                                                                       \
        const int srcl = ((CT)>>1)*16 + l15;                                    \
        _Pragma("unroll") for (int nt = 0; nt < 8; ++nt){                       \
            float vA = __shfl(chv[nt][2*(P)],   srcl);                          \
            float vB = __shfl(chv[nt][2*(P)+1], srcl);                          \
            float ch = (quad >= 2) ? vB : vA;                                   \
            float b = bxr[nt];                                                  \
            float h0 = relu(acch[nt][0]+b), h1 = relu(acch[nt][1]+b);           \
            float h2 = relu(acch[nt][2]+b), h3 = relu(acch[nt][3]+b);           \
            float s = h0+h1+h2+h3;                                              \
            int col = nt*16 + l15;                                              \
            lds_st[stoff + swz(quad*4+0, col)] = tobf((ch+s-h0)*0.25f);         \
            lds_st[stoff + swz(quad*4+1, col)] = tobf((ch+s-h1)*0.25f);         \
            lds_st[stoff + swz(quad*4+2, col)] = tobf((ch+s-h2)*0.25f);         \
            lds_st[stoff + swz(quad*4+3, col)] = tobf((ch+s-h3)*0.25f);         \
        }                                                                       \
        bf16x8 cf[4];                                                           \
        _Pragma("unroll") for (int ks = 0; ks < 4; ++ks)                        \
            cf[ks] = *(const bf16x8*)&lds_st[stoff + swz(l15, ks*32 + quad*8)]; \
        f32x4 accf[8];                                                          \
        _Pragma("unroll") for (int i = 0; i < 8; ++i) accf[i] = f32x4{0.f,0.f,0.f,0.f}; \
        _Pragma("unroll") for (int ks = 0; ks < 4; ++ks){                       \
            _Pragma("unroll") for (int nt = 0; nt < 8; ++nt){                   \
                bf16x8 b0 = *(const bf16x8*)&lds_wf[((nt*4+ks)<<9) + lane*8];           \
                bf16x8 b1 = *(const bf16x8*)&lds_wf[16384 + ((nt*4+ks)<<9) + lane*8];   \
                mfma_acc(accf[nt], cf[ks], b0);                                 \
                mfma_acc(accf[nt], AF[ks], b1);                                 \
            }                                                                   \
        }                                                                       \
        float p0=0.f,p1=0.f,p2=0.f,p3=0.f;                                      \
        _Pragma("unroll") for (int nt = 0; nt < 8; ++nt){                       \
            float b = bfr[nt], wh = whr[nt];                                    \
            p0 += relu(accf[nt][0]+b)*wh; p1 += relu(accf[nt][1]+b)*wh;         \
            p2 += relu(accf[nt][2]+b)*wh; p3 += relu(accf[nt][3]+b)*wh;         \
        }                                                                       \
        _Pragma("unroll") for (int m = 1; m < 16; m <<= 1){                     \
            p0 += __shfl_xor(p0, m); p1 += __shfl_xor(p1, m);                   \
            p2 += __shfl_xor(p2, m); p3 += __shfl_xor(p3, m);                   \
        }                                                                       \
        if (l15 == 0){                                                          \
            long long r = cb + task*128 + (long long)(CT)*16 + quad*4;          \
            out[r] = p0 + bb; out[r+1] = p1 + bb;                               \
            out[r+2] = p2 + bb; out[r+3] = p3 + bb;                             \
        }                                                                       \
    }

    auto LOADA = [&](bf16x8* d, int ct){
        const float* p = init + (cb + task*128 + ct*16 + l15)*DIM + quad*8;
        #pragma unroll
        for (int ks = 0; ks < 4; ++ks){
            float4 v0 = *(const float4*)(p + ks*32);
            float4 v1 = *(const float4*)(p + ks*32 + 4);
            bf16x8 a;
            a[0]=tobf(v0.x); a[1]=tobf(v0.y); a[2]=tobf(v0.z); a[3]=tobf(v0.w);
            a[4]=tobf(v1.x); a[5]=tobf(v1.y); a[6]=tobf(v1.z); a[7]=tobf(v1.w);
            d[ks] = a;
        }
    };

    bf16x8 aA[4], aB[4];
    LOADA(aA, 0);
    #pragma unroll 1
    for (int cp = 0; cp < 4; ++cp){
        const int ct0 = cp*2, ct1 = ct0 + 1;
        LOADA(aB, ct1);
        DF_TILE(ct0, 0, aA);
        if (cp < 3) LOADA(aA, ct0 + 2);
        DF_TILE(ct1, 1, aB);
    }
#undef DF_TILE

    // ---- fused final head for the 37449 non-leaf rows (R4..R11-proven body).
    // lds_wf untouched since the initial barrier -> no sync needed. 1171 tiles
    // over 2048 wave-slots: each wave does at most one tile.
    {
        const long long nrows = 37449LL;
        const long long r0f = ((long long)blockIdx.x*8 + w)*32;
        if (r0f < nrows){
            f32x4 acc[2][8];
            #pragma unroll
            for (int tt = 0; tt < 2; ++tt)
                #pragma unroll
                for (int i = 0; i < 8; ++i) acc[tt][i] = f32x4{0.f,0.f,0.f,0.f};
            #pragma unroll
            for (int half = 0; half < 2; ++half){
                const __bf16* src = half ? agg : ctx;
                bf16x8 a[2][4];
                #pragma unroll
                for (int tt = 0; tt < 2; ++tt){
                    long long r = r0f + tt*16 + l15;
                    if (r >= nrows) r = nrows - 1;
                    #pragma unroll
                    for (int ks = 0; ks < 4; ++ks)
                        a[tt][ks] = *(const bf16x8*)(src + r*DIM + ks*32 + quad*8);
                }
                #pragma unroll
                for (int ks = 0; ks < 4; ++ks){
                    #pragma unroll
                    for (int nt = 0; nt < 8; ++nt){
                        bf16x8 b = *(const bf16x8*)&lds_wf[half*16384 + ((nt*4+ks)<<9) + lane*8];
                        mfma_acc(acc[0][nt], a[0][ks], b);
                        mfma_acc(acc[1][nt], a[1][ks], b);
                    }
                }
            }
            #pragma unroll
            for (int tt = 0; tt < 2; ++tt){
                float p0 = 0.f, p1 = 0.f, p2 = 0.f, p3 = 0.f;
                #pragma unroll
                for (int nt = 0; nt < 8; ++nt){
                    float b = bfr[nt], wh = whr[nt];
                    p0 += relu(acc[tt][nt][0]+b)*wh;
                    p1 += relu(acc[tt][nt][1]+b)*wh;
                    p2 += relu(acc[tt][nt][2]+b)*wh;
                    p3 += relu(acc[tt][nt][3]+b)*wh;
                }
                #pragma unroll
                for (int m = 1; m < 16; m <<= 1){
                    p0 += __shfl_xor(p0, m);
                    p1 += __shfl_xor(p1, m);
                    p2 += __shfl_xor(p2, m);
                    p3 += __shfl_xor(p3, m);
                }
                if (l15 == 0){
                    long long r = r0f + tt*16 + quad*4;
                    if (r   < nrows) out[r  ] = p0 + bb;
                    if (r+1 < nrows) out[r+1] = p1 + bb;
                    if (r+2 < nrows) out[r+2] = p2 + bb;
                    if (r+3 < nrows) out[r+3] = p3 + bb;
                }
            }
        }
    }
}

// ================== fused small-level kernels (round-0 proven; levels 3,4 only) =====

__global__ __launch_bounds__(256, 3) void up_f(
    const __bf16* __restrict__ wts,     // Ws @0, Wc @16384 (row-major)
    const float* __restrict__ init,
    const float* __restrict__ bs, const float* __restrict__ bc,
    __bf16* __restrict__ agg,
    long long child_base, long long parent_base, long long n_par)
{
    __shared__ __bf16 lds_w[128*LPAD];
    __shared__ __bf16 lds_sib[32*LPAD];

    const int t = threadIdx.x;
    const int w = t >> 6, lane = t & 63, quad = lane >> 4, l15 = lane & 15;

    load_w_lds(wts, lds_w, 128);                // Ws
    __syncthreads();

    const long long n_child = n_par * 8;
    const long long rowbase = (long long)blockIdx.x*128 + w*32;

    f32x4 acc[2][8];
    #pragma unroll
    for (int tt = 0; tt < 2; ++tt)
        #pragma unroll
        for (int i = 0; i < 8; ++i) acc[tt][i] = f32x4{0.f,0.f,0.f,0.f};

    bf16x8 af[2][4];
    #pragma unroll
    for (int tt = 0; tt < 2; ++tt){
        long long r = rowbase + tt*16 + l15;
        if (r >= n_child) r = n_child - 1;
        const long long base = (child_base + r)*DIM;
        #pragma unroll
        for (int ks = 0; ks < 4; ++ks)
            af[tt][ks] = *(const bf16x8*)(agg + base + ks*32 + quad*8);
    }
    #pragma unroll
    for (int ks = 0; ks < 4; ++ks){
        #pragma unroll
        for (int nt = 0; nt < 8; ++nt){
            bf16x8 bfrag = *(const bf16x8*)&lds_w[(nt*16 + l15)*LPAD + ks*32 + quad*8];
            mfma_acc(acc[0][nt], af[0][ks], bfrag);
            mfma_acc(acc[1][nt], af[1][ks], bfrag);
        }
    }
    #pragma unroll
    for (int tt = 0; tt < 2; ++tt){
        const int g = w*8 + tt*4 + quad;
        #pragma unroll
        for (int nt = 0; nt < 8; ++nt){
            int col = nt*16 + l15;
            float b = bs[col];
            float s = relu(acc[tt][nt][0]+b) + relu(acc[tt][nt][1]+b)
                    + relu(acc[tt][nt][2]+b) + relu(acc[tt][nt][3]+b);
            lds_sib[g*LPAD + col] = tobf(s * 0.25f);
        }
    }
    __syncthreads();
    load_w_lds(wts + 16384, lds_w, 128);        // Wc (reuse LDS)
    __syncthreads();

    if (w < 2){
        f32x4 a2c[8];
        #pragma unroll
        for (int i = 0; i < 8; ++i) a2c[i] = f32x4{0.f,0.f,0.f,0.f};
        bf16x8 a2[4];
        #pragma unroll
        for (int ks = 0; ks < 4; ++ks)
            a2[ks] = *(const bf16x8*)&lds_sib[(w*16 + l15)*LPAD + ks*32 + quad*8];
        #pragma unroll
        for (int ks = 0; ks < 4; ++ks){
            #pragma unroll
            for (int nt = 0; nt < 8; ++nt){
                bf16x8 bfrag = *(const bf16x8*)&lds_w[(nt*16 + l15)*LPAD + ks*32 + quad*8];
                mfma_acc(a2c[nt], a2[ks], bfrag);
            }
        }
        const long long p0 = (long long)blockIdx.x*16 + w*8 + quad*2;
        const long long p1 = p0 + 1;
        #pragma unroll
        for (int nt = 0; nt < 8; ++nt){
            int col = nt*16 + l15;
            float b = bc[col];
            float r0 = relu(a2c[nt][0]+b), r1 = relu(a2c[nt][1]+b);
            float r2 = relu(a2c[nt][2]+b), r3 = relu(a2c[nt][3]+b);
            if (p0 < n_par){
                long long gr = parent_base + p0;
                agg[gr*DIM + col] = tobf(init[gr*DIM + col] + 0.5f*(r0+r1));
            }
            if (p1 < n_par){
                long long gr = parent_base + p1;
                agg[gr*DIM + col] = tobf(init[gr*DIM + col] + 0.5f*(r2+r3));
            }
        }
    }
}

__global__ __launch_bounds__(256, 3) void down_f(
    const __bf16* __restrict__ wts,     // Wx @32768 (row-major)
    const float* __restrict__ bx,
    const __bf16* __restrict__ agg,
    __bf16* __restrict__ ctx,
    long long parent_base, long long child_base, long long n_par)
{
    __shared__ __bf16 lds_w[128*LPAD];
    __shared__ float lds_ctxh[16*132];

    const int t = threadIdx.x;
    const int w = t >> 6, lane = t & 63, quad = lane >> 4, l15 = lane & 15;

    load_w_lds(wts + 32768, lds_w, 128);        // Wx
    __syncthreads();

    const long long n_child = n_par*8;

    if (w == 0){
        f32x4 acc[8];
        #pragma unroll
        for (int i = 0; i < 8; ++i) acc[i] = f32x4{0.f,0.f,0.f,0.f};
        bf16x8 a[4];
        long long p = (long long)blockIdx.x*16 + l15;
        if (p >= n_par) p = n_par - 1;
        #pragma unroll
        for (int ks = 0; ks < 4; ++ks)
            a[ks] = *(const bf16x8*)(ctx + (parent_base + p)*DIM + ks*32 + quad*8);
        #pragma unroll
        for (int ks = 0; ks < 4; ++ks){
            #pragma unroll
            for (int nt = 0; nt < 8; ++nt){
                bf16x8 bfrag = *(const bf16x8*)&lds_w[(nt*16 + l15)*LPAD + ks*32 + quad*8];
                mfma_acc(acc[nt], a[ks], bfrag);
            }
        }
        #pragma unroll
        for (int nt = 0; nt < 8; ++nt){
            int col = nt*16 + l15;
            float b = bx[col];
            #pragma unroll
            for (int rg = 0; rg < 4; ++rg)
                lds_ctxh[(quad*4 + rg)*132 + col] = relu(acc[nt][rg] + b);
        }
    }
    __syncthreads();

    f32x4 acc[2][8];
    #pragma unroll
    for (int tt = 0; tt < 2; ++tt)
        #pragma unroll
        for (int i = 0; i < 8; ++i) acc[tt][i] = f32x4{0.f,0.f,0.f,0.f};
    bf16x8 a[2][4];
    const long long rowbase = (long long)blockIdx.x*128 + w*32;
    #pragma unroll
    for (int tt = 0; tt < 2; ++tt){
        long long r = rowbase + tt*16 + l15;
        if (r >= n_child) r = n_child - 1;
        #pragma unroll
        for (int ks = 0; ks < 4; ++ks)
            a[tt][ks] = *(const bf16x8*)(agg + (child_base + r)*DIM + ks*32 + quad*8);
    }
    #pragma unroll
    for (int ks = 0; ks < 4; ++ks){
        #pragma unroll
        for (int nt = 0; nt < 8; ++nt){
            bf16x8 bfrag = *(const bf16x8*)&lds_w[(nt*16 + l15)*LPAD + ks*32 + quad*8];
            mfma_acc(acc[0][nt], a[0][ks], bfrag);
            mfma_acc(acc[1][nt], a[1][ks], bfrag);
        }
    }
    #pragma unroll
    for (int tt = 0; tt < 2; ++tt){
        const long long rb = rowbase + tt*16 + quad*4;
        const int p_loc = w*4 + tt*2 + (quad >> 1);
        #pragma unroll
        for (int nt = 0; nt < 8; ++nt){
            int col = nt*16 + l15;
            float b = bx[col];
            float h0 = relu(acc[tt][nt][0]+b), h1 = relu(acc[tt][nt][1]+b);
            float h2 = relu(acc[tt][nt][2]+b), h3 = relu(acc[tt][nt][3]+b);
            float s = h0 + h1 + h2 + h3;
            float ch = lds_ctxh[p_loc*132 + col];
            if (rb   < n_child) ctx[(child_base + rb  )*DIM + col] = tobf((ch + s - h0)*0.25f);
            if (rb+1 < n_child) ctx[(child_base + rb+1)*DIM + col] = tobf((ch + s - h1)*0.25f);
            if (rb+2 < n_child) ctx[(child_base + rb+2)*DIM + col] = tobf((ch + s - h2)*0.25f);
            if (rb+3 < n_child) ctx[(child_base + rb+3)*DIM + col] = tobf((ch + s - h3)*0.25f);
        }
    }
}

extern "C" void kernel_launch(void* const* d_in, const int* in_sizes, int n_in,
                              void* d_out, int out_size, void* d_ws, size_t ws_size,
                              hipStream_t stream)
{
    const float* init = (const float*)d_in[0];
    const float* Ws  = (const float*)d_in[1];
    const float* bs  = (const float*)d_in[2];
    const float* Wc  = (const float*)d_in[3];
    const float* bc  = (const float*)d_in[4];
    const float* Wx  = (const float*)d_in[5];
    const float* bx  = (const float*)d_in[6];
    const float* Wf  = (const float*)d_in[7];
    const float* bff = (const float*)d_in[8];
    const float* Wh  = (const float*)d_in[9];
    const float* bh  = (const float*)d_in[10];
    float* out = (float*)d_out;

    // ws layout: agg bf16 [N,128] | ctx bf16 [N,128] | wts row-major (81920)
    //            | wfm frag-major (81920)
    __bf16* agg = (__bf16*)d_ws;
    __bf16* ctx = agg + NTOT*DIM;
    __bf16* wts = ctx + NTOT*DIM;
    __bf16* wfm = wts + 81920;

    prep_kernel<<<dim3(641), dim3(256), 0, stream>>>(Ws, Wc, Wx, Wf, wts, ctx);

    // ---- up: leaf (level 5) barrier-free; levels 4,3 round-0 fused ----
    upleaf_kernel<<<dim3(1024), dim3(256), 0, stream>>>(wfm, init, bs, bc, agg);
    up_f<<<dim3(256), dim3(256), 0, stream>>>(wts, init, bs, bc, agg,
                                              4681LL, 585LL, 4096LL);   // level 4
    up_f<<<dim3(32), dim3(256), 0, stream>>>(wts, init, bs, bc, agg,
                                             585LL, 73LL, 512LL);       // level 3
    // ---- up levels 2..0 AND down levels 0..2 in ONE single-workgroup kernel ----
    tails_kernel<<<dim3(1), dim3(512), 0, stream>>>(wfm, wfm + 32768, init,
                                                    bs, bc, bx, agg, ctx);
    // ---- down levels 3,4 round-0 fused ----
    down_f<<<dim3(32), dim3(256), 0, stream>>>(wts, bx, agg, ctx,
                                               73LL, 585LL, 512LL);     // level 3
    down_f<<<dim3(256), dim3(256), 0, stream>>>(wts, bx, agg, ctx,
                                                585LL, 4681LL, 4096LL); // level 4
    // ---- leaf down-step + final head + fused non-leaf final (one kernel) ----
    downfinal_kernel<<<dim3(256), dim3(512), 0, stream>>>(
        wfm + 32768, wfm + 49152, bx, bff, Wh, bh, init, ctx, agg, out);
}